// Round 2
// baseline (689.787 us; speedup 1.0000x reference)
//
#include <hip/hip_runtime.h>
#include <stdint.h>

typedef unsigned short u16;
typedef unsigned int   u32;

#define NG   512
#define NPG  200
#define EPG  6400
#define NN   (NG*NPG)     // 102400 nodes
#define NE_  (NG*EPG)     // 3276800 edges
#define HID  128

__device__ __forceinline__ float bf2f(u16 b){ u32 u = ((u32)b) << 16; return __builtin_bit_cast(float, u); }
__device__ __forceinline__ u16 f2bf(float f){
    u32 u = __builtin_bit_cast(u32, f);
    u = (u + 0x7FFFu + ((u >> 16) & 1u)) >> 16;
    return (u16)u;
}
__device__ __forceinline__ float bfLo(u32 w){ return __builtin_bit_cast(float, w << 16); }
__device__ __forceinline__ float bfHi(u32 w){ return __builtin_bit_cast(float, w & 0xFFFF0000u); }

// Canonical fp32 weight-region element offsets
enum : int {
  O_W1 = 0,        O_b1 = 128,      O_W2 = 256,      O_b2 = 16640,
  O_Wa = 16768,    O_ba = 82304,    O_Wb = 82816,    O_bb = 607104,
  O_Wc = 608128,   O_bc = 1656704,  O_Wd = 1657728,  O_bd = 2182016,
  O_We = 2182528,  O_be = 2187648,  O_END = 2187658
};

// ---------------------------------------------------------------------------
// K0a: dtype detector. W1 ~ U(-1,1): as bf16 every u16 has exp<=0x7E.
// As fp32, the 64 mantissa-low u16s are ~random: ~32 have exp>=0x7F.
// flag = 1 -> inputs are fp32; flag = 0 -> inputs are bf16.
// ---------------------------------------------------------------------------
__global__ __launch_bounds__(128) void k_detect(const u16* __restrict__ w1bits,
                                                int* __restrict__ flag)
{
    __shared__ int cnt;
    const int tid = threadIdx.x;
    if (tid == 0) cnt = 0;
    __syncthreads();
    u16 u = w1bits[tid];
    int e = (u >> 7) & 0xFF;
    if (e >= 0x7F) atomicAdd(&cnt, 1);
    __syncthreads();
    if (tid == 0) *flag = (cnt > 4) ? 1 : 0;
}

// ---------------------------------------------------------------------------
// K0b: canonicalize all 14 float tensors to fp32 in ws (reads per flag).
// ---------------------------------------------------------------------------
struct Cvt { const void* src[14]; int off[15]; };

__global__ __launch_bounds__(256) void k_convert(Cvt c, float* __restrict__ dst,
                                                 const int* __restrict__ flag, int total)
{
    const int f = *flag;
    int i = blockIdx.x * 256 + threadIdx.x;
    if (i >= total) return;
    int t = 0;
    while (i >= c.off[t+1]) t++;
    int j = i - c.off[t];
    dst[i] = f ? ((const float*)c.src[t])[j] : bf2f(((const u16*)c.src[t])[j]);
}

// ---------------------------------------------------------------------------
// K1: per-graph: degrees, inv factors, counting-sort edges by dst,
//     layer-1 gconv (rank-1 trick: scalar edge aggregation), write h1 (bf16).
// ---------------------------------------------------------------------------
__global__ __launch_bounds__(256) void k_graph_l1(
    const int* __restrict__ src, const int* __restrict__ dst,
    const float* __restrict__ W1, const float* __restrict__ b1,
    float* __restrict__ invOutG, float* __restrict__ invInG,
    int*   __restrict__ rowStartG, u16* __restrict__ sortedSrcG,
    u16*   __restrict__ h1)
{
    __shared__ u16 srcL[EPG];
    __shared__ u16 dstL[EPG];
    __shared__ u16 sortedL[EPG];
    __shared__ int degIn[256];      // padded to 256 for the scan
    __shared__ int degOut[NPG];
    __shared__ int scanBuf[256];
    __shared__ int cursor[NPG];
    __shared__ float sVal[NPG], sAgg[NPG], invInL[NPG], invOutL[NPG], tL[NPG];
    __shared__ float w1L[HID], b1L[HID];

    const int g = blockIdx.x, tid = threadIdx.x;

    degIn[tid] = 0;
    if (tid < NPG){ degOut[tid] = 0; sAgg[tid] = 0.f; }
    if (tid < HID){ w1L[tid] = W1[tid]; b1L[tid] = b1[tid]; }
    __syncthreads();

    const int ebase = g * EPG;
    for (int i = 0; i < EPG/256; i++){
        int e = i*256 + tid;
        int s = src[ebase + e] - g*NPG;
        int d = dst[ebase + e] - g*NPG;
        srcL[e] = (u16)s; dstL[e] = (u16)d;
        atomicAdd(&degOut[s], 1);
        atomicAdd(&degIn[d], 1);
    }
    __syncthreads();

    if (tid < NPG){
        int din = degIn[tid], dout = degOut[tid];
        float ii = rsqrtf(fmaxf((float)din, 1.f));
        float io = rsqrtf(fmaxf((float)dout, 1.f));
        invInL[tid] = ii; invOutL[tid] = io;
        sVal[tid] = (float)din * io;              // h0 = in_deg; s = h0*inv_out
        invInG[g*NPG + tid] = ii;
        invOutG[g*NPG + tid] = io;
    }

    // inclusive Hillis-Steele scan of degIn[0..255]
    int x = degIn[tid];
    scanBuf[tid] = x;
    __syncthreads();
    for (int off = 1; off < 256; off <<= 1){
        int y = (tid >= off) ? scanBuf[tid - off] : 0;
        __syncthreads();
        x += y;
        scanBuf[tid] = x;
        __syncthreads();
    }
    if (tid < NPG){
        int st = scanBuf[tid] - degIn[tid];       // exclusive prefix
        cursor[tid] = st;
        rowStartG[g*NPG + tid] = st;
    }
    __syncthreads();

    // counting-sort scatter + scalar layer-1 aggregation
    for (int i = 0; i < EPG/256; i++){
        int e = i*256 + tid;
        int s = srcL[e], d = dstL[e];
        int pos = atomicAdd(&cursor[d], 1);
        sortedL[pos] = (u16)s;
        atomicAdd(&sAgg[d], sVal[s]);
    }
    __syncthreads();

    if (tid < NPG) tL[tid] = sAgg[tid] * invInL[tid];
    for (int i = 0; i < EPG/256; i++){
        int e = i*256 + tid;
        sortedSrcG[ebase + e] = sortedL[e];
    }
    __syncthreads();

    // h1[v][c] = relu(tL[v]*W1[c] + b1[c])
    const size_t hbase = (size_t)g * NPG * HID;
    for (int i = 0; i < NPG*HID/256; i++){
        int idx = i*256 + tid;
        int v = idx >> 7, c = idx & 127;
        float val = fmaxf(fmaf(tL[v], w1L[c], b1L[c]), 0.f);
        h1[hbase + idx] = f2bf(val);
    }
}

// ---------------------------------------------------------------------------
// Generic fp32-accumulate tiled GEMM: out = maybe_relu((A@W)*rowScale + bias)
// A: bf16 or fp32 (AF32); W/bias: canonical fp32; out: bf16 or fp32 (OF32).
// Requires M%BM==0, Nc%BN==0, K%32==0.
// ---------------------------------------------------------------------------
template<int BM, int BN, int TM, int TN, bool AF32, bool OF32>
__global__ __launch_bounds__(256) void k_gemm(
    const void* __restrict__ Av, const float* __restrict__ W,
    const float* __restrict__ bias, const float* __restrict__ rowScale,
    void* __restrict__ outv, int K, int Nc, int doRelu)
{
    constexpr int BK = 32;
    __shared__ __align__(16) float As[BK][BM + 4];   // transposed: As[k][m]
    __shared__ __align__(16) float Ws[BK][BN + 4];
    const int row0 = blockIdx.x * BM, col0 = blockIdx.y * BN;
    const int tid = threadIdx.x;
    constexpr int NTN = BN / TN;
    const int tm = (tid / NTN) * TM;
    const int tn = (tid % NTN) * TN;

    const u16*   Ab = (const u16*)Av;
    const float* Af = (const float*)Av;

    float acc[TM][TN];
    #pragma unroll
    for (int i = 0; i < TM; i++)
        #pragma unroll
        for (int j = 0; j < TN; j++) acc[i][j] = 0.f;

    for (int k0 = 0; k0 < K; k0 += BK){
        for (int idx = tid; idx < BM*BK; idx += 256){
            int r = idx >> 5, kk = idx & 31;
            size_t gi = (size_t)(row0 + r) * K + k0 + kk;
            As[kk][r] = AF32 ? Af[gi] : bf2f(Ab[gi]);
        }
        for (int idx = tid; idx < BK*BN; idx += 256){
            int kk = idx / BN, c = idx % BN;
            Ws[kk][c] = W[(size_t)(k0 + kk) * Nc + col0 + c];
        }
        __syncthreads();
        #pragma unroll
        for (int kk = 0; kk < BK; kk++){
            float a[TM], b[TN];
            if constexpr (TM == 4){
                float4 t = *(const float4*)&As[kk][tm];
                a[0]=t.x; a[1]=t.y; a[2]=t.z; a[3]=t.w;
            } else {
                float2 t = *(const float2*)&As[kk][tm];
                a[0]=t.x; a[1]=t.y;
            }
            if constexpr (TN == 8){
                float4 t0 = *(const float4*)&Ws[kk][tn];
                float4 t1 = *(const float4*)&Ws[kk][tn+4];
                b[0]=t0.x; b[1]=t0.y; b[2]=t0.z; b[3]=t0.w;
                b[4]=t1.x; b[5]=t1.y; b[6]=t1.z; b[7]=t1.w;
            } else {
                float4 t = *(const float4*)&Ws[kk][tn];
                b[0]=t.x; b[1]=t.y; b[2]=t.z; b[3]=t.w;
            }
            #pragma unroll
            for (int i = 0; i < TM; i++)
                #pragma unroll
                for (int j = 0; j < TN; j++)
                    acc[i][j] = fmaf(a[i], b[j], acc[i][j]);
        }
        __syncthreads();
    }

    #pragma unroll
    for (int i = 0; i < TM; i++){
        int r = row0 + tm + i;
        float rs = rowScale ? rowScale[r] : 1.f;
        #pragma unroll
        for (int j = 0; j < TN; j++){
            float v = acc[i][j] * rs;
            if (bias) v += bias[col0 + tn + j];
            if (doRelu) v = fmaxf(v, 0.f);
            size_t go = (size_t)r * Nc + col0 + tn + j;
            if constexpr (OF32) ((float*)outv)[go] = v;
            else                ((u16*)outv)[go] = f2bf(v);
        }
    }
}

// ---------------------------------------------------------------------------
// K3: per-graph: agg[v] = sum_{in-edges} M2[src]; h2 = relu(agg*invIn + b2);
//     hg[g] = mean_v h2  (h2 never hits global memory). CSR gather, reg acc.
// ---------------------------------------------------------------------------
__global__ __launch_bounds__(256) void k_agg_pool(
    const u16* __restrict__ M2, const int* __restrict__ rowStartG,
    const u16* __restrict__ sortedSrcG, const float* __restrict__ invInG,
    const float* __restrict__ b2, float* __restrict__ hg)
{
    __shared__ __align__(16) u16 inT[NPG][64];   // half the feature dim
    __shared__ u16 sortedL[EPG];
    __shared__ int rowSt[NPG + 1];
    __shared__ float invInL[NPG];
    __shared__ float b2L[HID];
    __shared__ float pool[HID];

    const int g = blockIdx.x, tid = threadIdx.x;
    for (int i = tid; i < EPG; i += 256) sortedL[i] = sortedSrcG[(size_t)g*EPG + i];
    if (tid < NPG){ rowSt[tid] = rowStartG[g*NPG + tid]; invInL[tid] = invInG[g*NPG + tid]; }
    if (tid == 0) rowSt[NPG] = EPG;
    if (tid < HID){ b2L[tid] = b2[tid]; pool[tid] = 0.f; }

    const size_t mbase = (size_t)g * NPG * HID;
    for (int half = 0; half < 2; half++){
        const int cb = half * 64;
        __syncthreads();   // also covers the initial staging before first use
        for (int idx = tid; idx < NPG*8; idx += 256){
            int v = idx >> 3, c8 = idx & 7;
            *(uint4*)&inT[v][c8*8] = *(const uint4*)&M2[mbase + (size_t)v*HID + cb + c8*8];
        }
        __syncthreads();
        const int cg = tid & 7;       // 8 threads per node, 8 cols each
        const int v0 = tid >> 3;      // 32 nodes concurrently
        for (int v = v0; v < NPG; v += 32){
            float a0=0,a1=0,a2=0,a3=0,a4=0,a5=0,a6=0,a7=0;
            const int e1 = rowSt[v+1];
            for (int e = rowSt[v]; e < e1; e++){
                int s = sortedL[e];
                uint4 raw = *(const uint4*)&inT[s][cg*8];
                a0 += bfLo(raw.x); a1 += bfHi(raw.x);
                a2 += bfLo(raw.y); a3 += bfHi(raw.y);
                a4 += bfLo(raw.z); a5 += bfHi(raw.z);
                a6 += bfLo(raw.w); a7 += bfHi(raw.w);
            }
            const float iv = invInL[v];
            const int c0 = cb + cg*8;
            float h;
            h = fmaxf(fmaf(a0, iv, b2L[c0+0]), 0.f); atomicAdd(&pool[c0+0], h);
            h = fmaxf(fmaf(a1, iv, b2L[c0+1]), 0.f); atomicAdd(&pool[c0+1], h);
            h = fmaxf(fmaf(a2, iv, b2L[c0+2]), 0.f); atomicAdd(&pool[c0+2], h);
            h = fmaxf(fmaf(a3, iv, b2L[c0+3]), 0.f); atomicAdd(&pool[c0+3], h);
            h = fmaxf(fmaf(a4, iv, b2L[c0+4]), 0.f); atomicAdd(&pool[c0+4], h);
            h = fmaxf(fmaf(a5, iv, b2L[c0+5]), 0.f); atomicAdd(&pool[c0+5], h);
            h = fmaxf(fmaf(a6, iv, b2L[c0+6]), 0.f); atomicAdd(&pool[c0+6], h);
            h = fmaxf(fmaf(a7, iv, b2L[c0+7]), 0.f); atomicAdd(&pool[c0+7], h);
        }
    }
    __syncthreads();
    if (tid < HID) hg[(size_t)g*HID + tid] = pool[tid] * (1.f / NPG);
}

// ---------------------------------------------------------------------------
// K5: head: logits = X4(512 fp32) @ We(512x10) + be; softmax -> out (dtype per flag)
// ---------------------------------------------------------------------------
__global__ __launch_bounds__(64) void k_head(
    const float* __restrict__ X, const float* __restrict__ We,
    const float* __restrict__ be, void* __restrict__ out,
    const int* __restrict__ flag)
{
    const int g = blockIdx.x, lane = threadIdx.x;
    float part[10];
    #pragma unroll
    for (int c = 0; c < 10; c++) part[c] = 0.f;
    for (int k = lane; k < 512; k += 64){
        float x = X[(size_t)g*512 + k];
        #pragma unroll
        for (int c = 0; c < 10; c++) part[c] = fmaf(x, We[k*10 + c], part[c]);
    }
    #pragma unroll
    for (int c = 0; c < 10; c++){
        float v = part[c];
        for (int off = 32; off > 0; off >>= 1) v += __shfl_down(v, off);
        part[c] = v;
    }
    if (lane == 0){
        const int f = *flag;
        #pragma unroll
        for (int c = 0; c < 10; c++) part[c] += be[c];
        float m = part[0];
        #pragma unroll
        for (int c = 1; c < 10; c++) m = fmaxf(m, part[c]);
        float e[10], s = 0.f;
        #pragma unroll
        for (int c = 0; c < 10; c++){ e[c] = __expf(part[c] - m); s += e[c]; }
        float inv = 1.f / s;
        #pragma unroll
        for (int c = 0; c < 10; c++){
            float p = e[c] * inv;
            if (f) ((float*)out)[g*10 + c] = p;
            else   ((u16*)out)[g*10 + c]  = f2bf(p);
        }
    }
}

// ---------------------------------------------------------------------------
extern "C" void kernel_launch(void* const* d_in, const int* in_sizes, int n_in,
                              void* d_out, int out_size, void* d_ws, size_t ws_size,
                              hipStream_t stream)
{
    const int* src = (const int*)d_in[0];
    const int* dst = (const int*)d_in[1];

    char* ws = (char*)d_ws;
    size_t o = 0;
    int*   flag     = (int*)  (ws + o); o += 16;
    float* wcanon   = (float*)(ws + o); o += ((size_t)O_END * 4 + 15) & ~(size_t)15;
    float* invOut   = (float*)(ws + o); o += (size_t)NN * 4;
    float* invIn    = (float*)(ws + o); o += (size_t)NN * 4;
    int*   rowStart = (int*)  (ws + o); o += (size_t)NN * 4;
    u16*   sortedSrc= (u16*)  (ws + o); o += (size_t)NE_ * 2;
    u16*   h1       = (u16*)  (ws + o); o += (size_t)NN * HID * 2;
    u16*   M2       = (u16*)  (ws + o); o += (size_t)NN * HID * 2;
    float* hg       = (float*)(ws + o); o += (size_t)NG * HID * 4;
    float* X1       = (float*)(ws + o); o += (size_t)NG * 512 * 4;
    float* X2       = (float*)(ws + o); o += (size_t)NG * 1024 * 4;
    float* X3       = (float*)(ws + o); o += (size_t)NG * 1024 * 4;
    float* X4       = (float*)(ws + o); o += (size_t)NG * 512 * 4;
    (void)ws_size; (void)in_sizes; (void)n_in; (void)out_size;

    // K0a: detect input float dtype (1 = fp32, 0 = bf16)
    k_detect<<<dim3(1), dim3(128), 0, stream>>>((const u16*)d_in[2], flag);

    // K0b: canonicalize all float tensors to fp32
    Cvt cv;
    const int offs[15] = {O_W1,O_b1,O_W2,O_b2,O_Wa,O_ba,O_Wb,O_bb,O_Wc,O_bc,O_Wd,O_bd,O_We,O_be,O_END};
    for (int i = 0; i < 14; i++){ cv.src[i] = d_in[2 + i]; cv.off[i] = offs[i]; }
    cv.off[14] = offs[14];
    k_convert<<<dim3((O_END + 255)/256), dim3(256), 0, stream>>>(cv, wcanon, flag, O_END);

    const float *W1 = wcanon+O_W1, *b1 = wcanon+O_b1, *W2 = wcanon+O_W2, *b2 = wcanon+O_b2;
    const float *Wa = wcanon+O_Wa, *ba = wcanon+O_ba, *Wb = wcanon+O_Wb, *bb = wcanon+O_bb;
    const float *Wc = wcanon+O_Wc, *bc = wcanon+O_bc, *Wd = wcanon+O_Wd, *bd = wcanon+O_bd;
    const float *We = wcanon+O_We, *be = wcanon+O_be;

    // K1: degrees + sort + layer1
    k_graph_l1<<<dim3(NG), dim3(256), 0, stream>>>(
        src, dst, W1, b1, invOut, invIn, rowStart, sortedSrc, h1);

    // K2: M2 = (h1 @ W2) * inv_out   [102400x128 @ 128x128] -> bf16
    k_gemm<64,128,4,8,false,false><<<dim3(NN/64, 1), dim3(256), 0, stream>>>(
        h1, W2, (const float*)nullptr, invOut, M2, HID, HID, 0);

    // K3: aggregate + bias/relu + mean-pool -> hg (fp32 512x128)
    k_agg_pool<<<dim3(NG), dim3(256), 0, stream>>>(
        M2, rowStart, sortedSrc, invIn, b2, hg);

    // MLP (fp32 activations, fp32 canonical weights)
    k_gemm<32,64,2,4,true,true><<<dim3(16, 8),  dim3(256), 0, stream>>>(
        hg, Wa, ba, (const float*)nullptr, X1, 128, 512, 1);
    k_gemm<32,64,2,4,true,true><<<dim3(16, 16), dim3(256), 0, stream>>>(
        X1, Wb, bb, (const float*)nullptr, X2, 512, 1024, 1);
    k_gemm<32,64,2,4,true,true><<<dim3(16, 16), dim3(256), 0, stream>>>(
        X2, Wc, bc, (const float*)nullptr, X3, 1024, 1024, 1);
    k_gemm<32,64,2,4,true,true><<<dim3(16, 8),  dim3(256), 0, stream>>>(
        X3, Wd, bd, (const float*)nullptr, X4, 1024, 512, 1);

    // head + softmax (output dtype per flag)
    k_head<<<dim3(NG), dim3(64), 0, stream>>>(X4, We, be, d_out, flag);
}

// Round 3
// 378.762 us; speedup vs baseline: 1.8212x; 1.8212x over previous
//
#include <hip/hip_runtime.h>
#include <stdint.h>

typedef unsigned short u16;
typedef unsigned int   u32;

#define NG   512
#define NPG  200
#define EPG  6400
#define NN   (NG*NPG)     // 102400 nodes
#define NE_  (NG*EPG)     // 3276800 edges
#define HID  128

__device__ __forceinline__ float bf2f(u16 b){ u32 u = ((u32)b) << 16; return __builtin_bit_cast(float, u); }
__device__ __forceinline__ u16 f2bf(float f){
    u32 u = __builtin_bit_cast(u32, f);
    u = (u + 0x7FFFu + ((u >> 16) & 1u)) >> 16;
    return (u16)u;
}
__device__ __forceinline__ float bfLo(u32 w){ return __builtin_bit_cast(float, w << 16); }
__device__ __forceinline__ float bfHi(u32 w){ return __builtin_bit_cast(float, w & 0xFFFF0000u); }

typedef __attribute__((ext_vector_type(8))) short bf16x8;
typedef __attribute__((ext_vector_type(4))) float f32x4;

// Canonical fp32 weight-region element offsets
enum : int {
  O_W1 = 0,        O_b1 = 128,      O_W2 = 256,      O_b2 = 16640,
  O_Wa = 16768,    O_ba = 82304,    O_Wb = 82816,    O_bb = 607104,
  O_Wc = 608128,   O_bc = 1656704,  O_Wd = 1657728,  O_bd = 2182016,
  O_We = 2182528,  O_be = 2187648,  O_END = 2187658
};

// ---------------------------------------------------------------------------
// K0a: dtype detector (1 = fp32 inputs, 0 = bf16 inputs)
// ---------------------------------------------------------------------------
__global__ __launch_bounds__(128) void k_detect(const u16* __restrict__ w1bits,
                                                int* __restrict__ flag)
{
    __shared__ int cnt;
    const int tid = threadIdx.x;
    if (tid == 0) cnt = 0;
    __syncthreads();
    u16 u = w1bits[tid];
    int e = (u >> 7) & 0xFF;
    if (e >= 0x7F) atomicAdd(&cnt, 1);
    __syncthreads();
    if (tid == 0) *flag = (cnt > 4) ? 1 : 0;
}

// ---------------------------------------------------------------------------
// K0b: canonicalize all 14 float tensors to fp32 in ws
// ---------------------------------------------------------------------------
struct Cvt { const void* src[14]; int off[15]; };

__global__ __launch_bounds__(256) void k_convert(Cvt c, float* __restrict__ dst,
                                                 const int* __restrict__ flag, int total)
{
    const int f = *flag;
    int i = blockIdx.x * 256 + threadIdx.x;
    if (i >= total) return;
    int t = 0;
    while (i >= c.off[t+1]) t++;
    int j = i - c.off[t];
    dst[i] = f ? ((const float*)c.src[t])[j] : bf2f(((const u16*)c.src[t])[j]);
}

// K0c: bf16 copy of W2 for the MFMA path (exact passthrough when inputs are bf16)
__global__ __launch_bounds__(256) void k_w2bf(const void* __restrict__ w2src,
                                              const float* __restrict__ w2canon,
                                              u16* __restrict__ W2bf,
                                              const int* __restrict__ flag)
{
    int i = blockIdx.x * 256 + threadIdx.x;
    if (i >= HID*HID) return;
    W2bf[i] = (*flag) ? f2bf(w2canon[i]) : ((const u16*)w2src)[i];
}

// ---------------------------------------------------------------------------
// K1: per-graph: degrees, inv factors, counting-sort edges by dst,
//     layer-1 gconv (rank-1 trick), write h1 (bf16).
// ---------------------------------------------------------------------------
__global__ __launch_bounds__(256) void k_graph_l1(
    const int* __restrict__ src, const int* __restrict__ dst,
    const float* __restrict__ W1, const float* __restrict__ b1,
    float* __restrict__ invOutG, float* __restrict__ invInG,
    int*   __restrict__ rowStartG, u16* __restrict__ sortedSrcG,
    u16*   __restrict__ h1)
{
    __shared__ u16 srcL[EPG];
    __shared__ u16 dstL[EPG];
    __shared__ u16 sortedL[EPG];
    __shared__ int degIn[256];
    __shared__ int degOut[NPG];
    __shared__ int scanBuf[256];
    __shared__ int cursor[NPG];
    __shared__ float sVal[NPG], sAgg[NPG], invInL[NPG], invOutL[NPG], tL[NPG];
    __shared__ float w1L[HID], b1L[HID];

    const int g = blockIdx.x, tid = threadIdx.x;

    degIn[tid] = 0;
    if (tid < NPG){ degOut[tid] = 0; sAgg[tid] = 0.f; }
    if (tid < HID){ w1L[tid] = W1[tid]; b1L[tid] = b1[tid]; }
    __syncthreads();

    const int ebase = g * EPG;
    #pragma unroll
    for (int i = 0; i < EPG/256; i++){
        int e = i*256 + tid;
        int s = src[ebase + e] - g*NPG;
        int d = dst[ebase + e] - g*NPG;
        srcL[e] = (u16)s; dstL[e] = (u16)d;
        atomicAdd(&degOut[s], 1);
        atomicAdd(&degIn[d], 1);
    }
    __syncthreads();

    if (tid < NPG){
        int din = degIn[tid], dout = degOut[tid];
        float ii = rsqrtf(fmaxf((float)din, 1.f));
        float io = rsqrtf(fmaxf((float)dout, 1.f));
        invInL[tid] = ii; invOutL[tid] = io;
        sVal[tid] = (float)din * io;
        invInG[g*NPG + tid] = ii;
        invOutG[g*NPG + tid] = io;
    }

    int x = degIn[tid];
    scanBuf[tid] = x;
    __syncthreads();
    for (int off = 1; off < 256; off <<= 1){
        int y = (tid >= off) ? scanBuf[tid - off] : 0;
        __syncthreads();
        x += y;
        scanBuf[tid] = x;
        __syncthreads();
    }
    if (tid < NPG){
        int st = scanBuf[tid] - degIn[tid];
        cursor[tid] = st;
        rowStartG[g*NPG + tid] = st;
    }
    __syncthreads();

    #pragma unroll
    for (int i = 0; i < EPG/256; i++){
        int e = i*256 + tid;
        int s = srcL[e], d = dstL[e];
        int pos = atomicAdd(&cursor[d], 1);
        sortedL[pos] = (u16)s;
        atomicAdd(&sAgg[d], sVal[s]);
    }
    __syncthreads();

    if (tid < NPG) tL[tid] = sAgg[tid] * invInL[tid];
    #pragma unroll
    for (int i = 0; i < EPG/256; i++){
        int e = i*256 + tid;
        sortedSrcG[ebase + e] = sortedL[e];
    }
    __syncthreads();

    const size_t hbase = (size_t)g * NPG * HID;
    #pragma unroll
    for (int i = 0; i < NPG*HID/256; i++){
        int idx = i*256 + tid;
        int v = idx >> 7, c = idx & 127;
        float val = fmaxf(fmaf(tL[v], w1L[c], b1L[c]), 0.f);
        h1[hbase + idx] = f2bf(val);
    }
}

// ---------------------------------------------------------------------------
// K2: MFMA bf16 GEMM: M2 = (h1 @ W2) * invOut, [NN x 128] @ [128 x 128] -> bf16
// One block = 64 rows; K=128 staged fully in LDS (no K loop).
// A-frag: A[m=lane&15][k=quad*8+j]; B-frag: B[k=quad*8+j][n=lane&15];
// C/D: col=lane&15, row=quad*4+reg   [per cdna4 docs, m89/m120]
// ---------------------------------------------------------------------------
__global__ __launch_bounds__(256) void k2_mfma(
    const u16* __restrict__ h1, const u16* __restrict__ W2bf,
    const float* __restrict__ invOut, u16* __restrict__ M2)
{
    __shared__ __align__(16) u16 Asl[64][136];    // +8 pad keeps 16B align, breaks bank stride
    __shared__ __align__(16) u16 Bsl[128][136];   // B transposed: Bsl[n][k]
    __shared__ float invL[64];

    const int tid = threadIdx.x;
    const int row0 = blockIdx.x * 64;

    #pragma unroll
    for (int i = 0; i < 4; i++){            // A: 64x128 bf16, uint4 chunks
        int c = i*256 + tid;
        int r = c >> 4, off = (c & 15) * 8;
        *(uint4*)&Asl[r][off] = *(const uint4*)&h1[(size_t)(row0 + r)*HID + off];
    }
    #pragma unroll
    for (int i = 0; i < 8; i++){            // B: 128x128 bf16, transpose into LDS
        int c = i*256 + tid;
        int k = c >> 4, n0 = (c & 15) * 8;
        uint4 v = *(const uint4*)&W2bf[k*HID + n0];
        const u16* pv = (const u16*)&v;
        #pragma unroll
        for (int j = 0; j < 8; j++) Bsl[n0 + j][k] = pv[j];
    }
    if (tid < 64) invL[tid] = invOut[row0 + tid];
    __syncthreads();

    const int w = tid >> 6;
    const int lane = tid & 63;
    const int lr = lane & 15, quad = lane >> 4;

    f32x4 acc[8];
    const f32x4 fz = {0.f, 0.f, 0.f, 0.f};
    #pragma unroll
    for (int nt = 0; nt < 8; nt++) acc[nt] = fz;

    #pragma unroll
    for (int ks = 0; ks < 4; ks++){
        bf16x8 af = *(const bf16x8*)&Asl[w*16 + lr][ks*32 + quad*8];
        #pragma unroll
        for (int nt = 0; nt < 8; nt++){
            bf16x8 bfr = *(const bf16x8*)&Bsl[nt*16 + lr][ks*32 + quad*8];
            acc[nt] = __builtin_amdgcn_mfma_f32_16x16x32_bf16(af, bfr, acc[nt], 0, 0, 0);
        }
    }
    __syncthreads();    // done reading Asl; reuse it as the output stage

    #pragma unroll
    for (int nt = 0; nt < 8; nt++){
        #pragma unroll
        for (int r = 0; r < 4; r++){
            int rr = w*16 + quad*4 + r;
            Asl[rr][nt*16 + lr] = f2bf(acc[nt][r] * invL[rr]);
        }
    }
    __syncthreads();

    #pragma unroll
    for (int i = 0; i < 4; i++){            // coalesced bf16 store
        int c = i*256 + tid;
        int r = c >> 4, off = (c & 15) * 8;
        *(uint4*)&M2[(size_t)(row0 + r)*HID + off] = *(const uint4*)&Asl[r][off];
    }
}

// ---------------------------------------------------------------------------
// K3: per-graph: agg[v] = sum_{in-edges} M2[src]; h2 = relu(agg*invIn + b2);
//     hg[g] = mean_v h2. CSR gather, register accumulation.
// ---------------------------------------------------------------------------
__global__ __launch_bounds__(256) void k_agg_pool(
    const u16* __restrict__ M2, const int* __restrict__ rowStartG,
    const u16* __restrict__ sortedSrcG, const float* __restrict__ invInG,
    const float* __restrict__ b2, float* __restrict__ hg)
{
    __shared__ __align__(16) u16 inT[NPG][64];
    __shared__ u16 sortedL[EPG];
    __shared__ int rowSt[NPG + 1];
    __shared__ float invInL[NPG];
    __shared__ float b2L[HID];
    __shared__ float pool[HID];

    const int g = blockIdx.x, tid = threadIdx.x;
    for (int i = tid; i < EPG; i += 256) sortedL[i] = sortedSrcG[(size_t)g*EPG + i];
    if (tid < NPG){ rowSt[tid] = rowStartG[g*NPG + tid]; invInL[tid] = invInG[g*NPG + tid]; }
    if (tid == 0) rowSt[NPG] = EPG;
    if (tid < HID){ b2L[tid] = b2[tid]; pool[tid] = 0.f; }

    const size_t mbase = (size_t)g * NPG * HID;
    for (int half = 0; half < 2; half++){
        const int cb = half * 64;
        __syncthreads();
        for (int idx = tid; idx < NPG*8; idx += 256){
            int v = idx >> 3, c8 = idx & 7;
            *(uint4*)&inT[v][c8*8] = *(const uint4*)&M2[mbase + (size_t)v*HID + cb + c8*8];
        }
        __syncthreads();
        const int cg = tid & 7;
        const int v0 = tid >> 3;
        for (int v = v0; v < NPG; v += 32){
            float a0=0,a1=0,a2=0,a3=0,a4=0,a5=0,a6=0,a7=0;
            const int e1 = rowSt[v+1];
            for (int e = rowSt[v]; e < e1; e++){
                int s = sortedL[e];
                uint4 raw = *(const uint4*)&inT[s][cg*8];
                a0 += bfLo(raw.x); a1 += bfHi(raw.x);
                a2 += bfLo(raw.y); a3 += bfHi(raw.y);
                a4 += bfLo(raw.z); a5 += bfHi(raw.z);
                a6 += bfLo(raw.w); a7 += bfHi(raw.w);
            }
            const float iv = invInL[v];
            const int c0 = cb + cg*8;
            float h;
            h = fmaxf(fmaf(a0, iv, b2L[c0+0]), 0.f); atomicAdd(&pool[c0+0], h);
            h = fmaxf(fmaf(a1, iv, b2L[c0+1]), 0.f); atomicAdd(&pool[c0+1], h);
            h = fmaxf(fmaf(a2, iv, b2L[c0+2]), 0.f); atomicAdd(&pool[c0+2], h);
            h = fmaxf(fmaf(a3, iv, b2L[c0+3]), 0.f); atomicAdd(&pool[c0+3], h);
            h = fmaxf(fmaf(a4, iv, b2L[c0+4]), 0.f); atomicAdd(&pool[c0+4], h);
            h = fmaxf(fmaf(a5, iv, b2L[c0+5]), 0.f); atomicAdd(&pool[c0+5], h);
            h = fmaxf(fmaf(a6, iv, b2L[c0+6]), 0.f); atomicAdd(&pool[c0+6], h);
            h = fmaxf(fmaf(a7, iv, b2L[c0+7]), 0.f); atomicAdd(&pool[c0+7], h);
        }
    }
    __syncthreads();
    if (tid < HID) hg[(size_t)g*HID + tid] = pool[tid] * (1.f / NPG);
}

// ---------------------------------------------------------------------------
// MLP GEMM, split-K: P[s] = A[:, s-chunk] @ W[s-chunk, :]   (fp32)
// Double-buffered LDS, fully unrolled register-prefetch staging.
// BM=32, BN=64, BK=32, TM=2, TN=4, 256 threads.
// ---------------------------------------------------------------------------
__global__ __launch_bounds__(256) void k_mlp(
    const float* __restrict__ A, const float* __restrict__ W,
    float* __restrict__ P, int K, int Nc, int chunk)
{
    constexpr int BM = 32, BN = 64, BK = 32;
    constexpr int LA = BM*BK/256;   // 4
    constexpr int LW = BK*BN/256;   // 8
    __shared__ __align__(16) float As[2][BK][BM + 4];
    __shared__ __align__(16) float Ws[2][BK][BN + 4];

    const int row0 = blockIdx.x * BM, col0 = blockIdx.y * BN, s = blockIdx.z;
    const int k0 = s * chunk;
    const int T = chunk / BK;
    const int tid = threadIdx.x;
    const int tm = (tid >> 4) * 2;          // 16 row-groups of 2
    const int tn = (tid & 15) * 4;          // 16 col-groups of 4

    float ra[LA], rw[LW];

    // ---- load tile 0 into regs, store to buf 0
    #pragma unroll
    for (int i = 0; i < LA; i++){
        int idx = i*256 + tid; int r = idx >> 5, kk = idx & 31;
        ra[i] = A[(size_t)(row0 + r)*K + k0 + kk];
    }
    #pragma unroll
    for (int i = 0; i < LW; i++){
        int idx = i*256 + tid; int kk = idx >> 6, c = idx & 63;
        rw[i] = W[(size_t)(k0 + kk)*Nc + col0 + c];
    }
    #pragma unroll
    for (int i = 0; i < LA; i++){
        int idx = i*256 + tid; int r = idx >> 5, kk = idx & 31;
        As[0][kk][r] = ra[i];
    }
    #pragma unroll
    for (int i = 0; i < LW; i++){
        int idx = i*256 + tid; int kk = idx >> 6, c = idx & 63;
        Ws[0][kk][c] = rw[i];
    }
    __syncthreads();

    float acc[2][4];
    #pragma unroll
    for (int i = 0; i < 2; i++)
        #pragma unroll
        for (int j = 0; j < 4; j++) acc[i][j] = 0.f;

    for (int t = 0; t < T-1; t++){
        const int buf = t & 1, nxt = buf ^ 1;
        const int kb = k0 + (t+1)*BK;
        // issue next-tile loads
        #pragma unroll
        for (int i = 0; i < LA; i++){
            int idx = i*256 + tid; int r = idx >> 5, kk = idx & 31;
            ra[i] = A[(size_t)(row0 + r)*K + kb + kk];
        }
        #pragma unroll
        for (int i = 0; i < LW; i++){
            int idx = i*256 + tid; int kk = idx >> 6, c = idx & 63;
            rw[i] = W[(size_t)(kb + kk)*Nc + col0 + c];
        }
        // compute current tile (overlaps the loads)
        #pragma unroll
        for (int kk = 0; kk < BK; kk++){
            float2 av = *(const float2*)&As[buf][kk][tm];
            float4 bv = *(const float4*)&Ws[buf][kk][tn];
            acc[0][0] = fmaf(av.x, bv.x, acc[0][0]); acc[0][1] = fmaf(av.x, bv.y, acc[0][1]);
            acc[0][2] = fmaf(av.x, bv.z, acc[0][2]); acc[0][3] = fmaf(av.x, bv.w, acc[0][3]);
            acc[1][0] = fmaf(av.y, bv.x, acc[1][0]); acc[1][1] = fmaf(av.y, bv.y, acc[1][1]);
            acc[1][2] = fmaf(av.y, bv.z, acc[1][2]); acc[1][3] = fmaf(av.y, bv.w, acc[1][3]);
        }
        // stage next tile
        #pragma unroll
        for (int i = 0; i < LA; i++){
            int idx = i*256 + tid; int r = idx >> 5, kk = idx & 31;
            As[nxt][kk][r] = ra[i];
        }
        #pragma unroll
        for (int i = 0; i < LW; i++){
            int idx = i*256 + tid; int kk = idx >> 6, c = idx & 63;
            Ws[nxt][kk][c] = rw[i];
        }
        __syncthreads();
    }
    {
        const int buf = (T-1) & 1;
        #pragma unroll
        for (int kk = 0; kk < BK; kk++){
            float2 av = *(const float2*)&As[buf][kk][tm];
            float4 bv = *(const float4*)&Ws[buf][kk][tn];
            acc[0][0] = fmaf(av.x, bv.x, acc[0][0]); acc[0][1] = fmaf(av.x, bv.y, acc[0][1]);
            acc[0][2] = fmaf(av.x, bv.z, acc[0][2]); acc[0][3] = fmaf(av.x, bv.w, acc[0][3]);
            acc[1][0] = fmaf(av.y, bv.x, acc[1][0]); acc[1][1] = fmaf(av.y, bv.y, acc[1][1]);
            acc[1][2] = fmaf(av.y, bv.z, acc[1][2]); acc[1][3] = fmaf(av.y, bv.w, acc[1][3]);
        }
    }

    float* Pd = P + (size_t)s * ( (size_t)512 * Nc );
    #pragma unroll
    for (int i = 0; i < 2; i++){
        int r = row0 + tm + i;
        float4 v = { acc[i][0], acc[i][1], acc[i][2], acc[i][3] };
        *(float4*)&Pd[(size_t)r * Nc + col0 + tn] = v;
    }
}

// Reduce S partials + bias + relu -> X (fp32), vectorized float4
__global__ __launch_bounds__(256) void k_reduce(
    const float* __restrict__ P, const float* __restrict__ bias,
    float* __restrict__ X, int MN, int Nc, int S)
{
    int e = blockIdx.x * 256 + threadIdx.x;
    int i0 = e * 4;
    if (i0 >= MN) return;
    float4 sum = *(const float4*)&P[i0];
    for (int s = 1; s < S; s++){
        float4 t = *(const float4*)&P[(size_t)s*MN + i0];
        sum.x += t.x; sum.y += t.y; sum.z += t.z; sum.w += t.w;
    }
    int col = i0 % Nc;
    float4 b = *(const float4*)&bias[col];
    sum.x = fmaxf(sum.x + b.x, 0.f);
    sum.y = fmaxf(sum.y + b.y, 0.f);
    sum.z = fmaxf(sum.z + b.z, 0.f);
    sum.w = fmaxf(sum.w + b.w, 0.f);
    *(float4*)&X[i0] = sum;
}

// ---------------------------------------------------------------------------
// K5: head: logits = X4(512 fp32) @ We(512x10) + be; softmax -> out per flag
// ---------------------------------------------------------------------------
__global__ __launch_bounds__(64) void k_head(
    const float* __restrict__ X, const float* __restrict__ We,
    const float* __restrict__ be, void* __restrict__ out,
    const int* __restrict__ flag)
{
    const int g = blockIdx.x, lane = threadIdx.x;
    float part[10];
    #pragma unroll
    for (int c = 0; c < 10; c++) part[c] = 0.f;
    for (int k = lane; k < 512; k += 64){
        float x = X[(size_t)g*512 + k];
        #pragma unroll
        for (int c = 0; c < 10; c++) part[c] = fmaf(x, We[k*10 + c], part[c]);
    }
    #pragma unroll
    for (int c = 0; c < 10; c++){
        float v = part[c];
        for (int off = 32; off > 0; off >>= 1) v += __shfl_down(v, off);
        part[c] = v;
    }
    if (lane == 0){
        const int f = *flag;
        #pragma unroll
        for (int c = 0; c < 10; c++) part[c] += be[c];
        float m = part[0];
        #pragma unroll
        for (int c = 1; c < 10; c++) m = fmaxf(m, part[c]);
        float e[10], s = 0.f;
        #pragma unroll
        for (int c = 0; c < 10; c++){ e[c] = __expf(part[c] - m); s += e[c]; }
        float inv = 1.f / s;
        #pragma unroll
        for (int c = 0; c < 10; c++){
            float p = e[c] * inv;
            if (f) ((float*)out)[g*10 + c] = p;
            else   ((u16*)out)[g*10 + c]  = f2bf(p);
        }
    }
}

// ---------------------------------------------------------------------------
extern "C" void kernel_launch(void* const* d_in, const int* in_sizes, int n_in,
                              void* d_out, int out_size, void* d_ws, size_t ws_size,
                              hipStream_t stream)
{
    const int* src = (const int*)d_in[0];
    const int* dst = (const int*)d_in[1];

    char* ws = (char*)d_ws;
    size_t o = 0;
    int*   flag     = (int*)  (ws + o); o += 16;
    float* wcanon   = (float*)(ws + o); o += ((size_t)O_END * 4 + 15) & ~(size_t)15;
    u16*   W2bf     = (u16*)  (ws + o); o += (size_t)HID * HID * 2;
    float* invOut   = (float*)(ws + o); o += (size_t)NN * 4;
    float* invIn    = (float*)(ws + o); o += (size_t)NN * 4;
    int*   rowStart = (int*)  (ws + o); o += (size_t)NN * 4;
    u16*   sortedSrc= (u16*)  (ws + o); o += (size_t)NE_ * 2;
    u16*   h1       = (u16*)  (ws + o); o += (size_t)NN * HID * 2;   // 26.2 MB
    u16*   M2       = (u16*)  (ws + o); o += (size_t)NN * HID * 2;
    float* hg       = (float*)(ws + o); o += (size_t)NG * HID * 4;
    float* X1       = (float*)(ws + o); o += (size_t)NG * 512 * 4;
    float* X2       = (float*)(ws + o); o += (size_t)NG * 1024 * 4;
    float* X3       = (float*)(ws + o); o += (size_t)NG * 1024 * 4;
    float* X4       = (float*)(ws + o); o += (size_t)NG * 512 * 4;
    float* Pp       = (float*)h1;   // split-K partials (8.4 MB) alias h1: h1 dead after K2
    (void)ws_size; (void)in_sizes; (void)n_in; (void)out_size;

    k_detect<<<dim3(1), dim3(128), 0, stream>>>((const u16*)d_in[2], flag);

    Cvt cv;
    const int offs[15] = {O_W1,O_b1,O_W2,O_b2,O_Wa,O_ba,O_Wb,O_bb,O_Wc,O_bc,O_Wd,O_bd,O_We,O_be,O_END};
    for (int i = 0; i < 14; i++){ cv.src[i] = d_in[2 + i]; cv.off[i] = offs[i]; }
    cv.off[14] = offs[14];
    k_convert<<<dim3((O_END + 255)/256), dim3(256), 0, stream>>>(cv, wcanon, flag, O_END);
    k_w2bf<<<dim3((HID*HID + 255)/256), dim3(256), 0, stream>>>(d_in[4], wcanon + O_W2, W2bf, flag);

    const float *W1 = wcanon+O_W1, *b1 = wcanon+O_b1, *b2 = wcanon+O_b2;
    const float *Wa = wcanon+O_Wa, *ba = wcanon+O_ba, *Wb = wcanon+O_Wb, *bb = wcanon+O_bb;
    const float *Wc = wcanon+O_Wc, *bc = wcanon+O_bc, *Wd = wcanon+O_Wd, *bd = wcanon+O_bd;
    const float *We = wcanon+O_We, *be = wcanon+O_be;

    // K1: degrees + sort + layer1
    k_graph_l1<<<dim3(NG), dim3(256), 0, stream>>>(
        src, dst, W1, b1, invOut, invIn, rowStart, sortedSrc, h1);

    // K2: M2 = (h1 @ W2) * inv_out, MFMA bf16
    k2_mfma<<<dim3(NN/64), dim3(256), 0, stream>>>(h1, W2bf, invOut, M2);

    // K3: aggregate + bias/relu + mean-pool -> hg (fp32 512x128)
    k_agg_pool<<<dim3(NG), dim3(256), 0, stream>>>(
        M2, rowStart, sortedSrc, invIn, b2, hg);

    // MLP: split-K GEMM + reduce(bias+relu).  (h1 region now free -> Pp)
    // La: 512x512, K=128, S=2
    k_mlp<<<dim3(16, 8, 2),  dim3(256), 0, stream>>>(hg, Wa, Pp, 128, 512, 64);
    k_reduce<<<dim3(512*512/1024), dim3(256), 0, stream>>>(Pp, ba, X1, 512*512, 512, 2);
    // Lb: 512x1024, K=512, S=4
    k_mlp<<<dim3(16, 16, 4), dim3(256), 0, stream>>>(X1, Wb, Pp, 512, 1024, 128);
    k_reduce<<<dim3(512*1024/1024), dim3(256), 0, stream>>>(Pp, bb, X2, 512*1024, 1024, 4);
    // Lc: 512x1024, K=1024, S=4
    k_mlp<<<dim3(16, 16, 4), dim3(256), 0, stream>>>(X2, Wc, Pp, 1024, 1024, 256);
    k_reduce<<<dim3(512*1024/1024), dim3(256), 0, stream>>>(Pp, bc, X3, 512*1024, 1024, 4);
    // Ld: 512x512, K=1024, S=4
    k_mlp<<<dim3(16, 8, 4),  dim3(256), 0, stream>>>(X3, Wd, Pp, 1024, 512, 256);
    k_reduce<<<dim3(512*512/1024), dim3(256), 0, stream>>>(Pp, bd, X4, 512*512, 512, 4);

    // head + softmax
    k_head<<<dim3(NG), dim3(64), 0, stream>>>(X4, We, be, d_out, flag);
}

// Round 4
// 299.629 us; speedup vs baseline: 2.3021x; 1.2641x over previous
//
#include <hip/hip_runtime.h>
#include <stdint.h>

typedef unsigned short u16;
typedef unsigned int   u32;

#define NG   512
#define NPG  200
#define EPG  6400
#define NN   (NG*NPG)     // 102400 nodes
#define NE_  (NG*EPG)     // 3276800 edges
#define HID  128
#define KP   224          // padded src-dim (K) for GEMM1, multiple of 32
#define AP   232          // dense-A row stride in u16 (16B-aligned, conflict-breaking)
#define ZP   136          // Z row stride in u16 (16B-aligned)
#define AZ_WORDS (208*AP) // 48256 u16 = 96512 B

__device__ __forceinline__ float bf2f(u16 b){ u32 u = ((u32)b) << 16; return __builtin_bit_cast(float, u); }
__device__ __forceinline__ u16 f2bf(float f){
    u32 u = __builtin_bit_cast(u32, f);
    u = (u + 0x7FFFu + ((u >> 16) & 1u)) >> 16;
    return (u16)u;
}

typedef __attribute__((ext_vector_type(8))) short bf16x8;
typedef __attribute__((ext_vector_type(4))) float f32x4;

// Canonical fp32 weight-region element offsets
enum : int {
  O_W1 = 0,        O_b1 = 128,      O_W2 = 256,      O_b2 = 16640,
  O_Wa = 16768,    O_ba = 82304,    O_Wb = 82816,    O_bb = 607104,
  O_Wc = 608128,   O_bc = 1656704,  O_Wd = 1657728,  O_bd = 2182016,
  O_We = 2182528,  O_be = 2187648,  O_END = 2187658
};

// ---------------------------------------------------------------------------
// K0a: dtype detector (1 = fp32 inputs, 0 = bf16 inputs)
// ---------------------------------------------------------------------------
__global__ __launch_bounds__(128) void k_detect(const u16* __restrict__ w1bits,
                                                int* __restrict__ flag)
{
    __shared__ int cnt;
    const int tid = threadIdx.x;
    if (tid == 0) cnt = 0;
    __syncthreads();
    u16 u = w1bits[tid];
    int e = (u >> 7) & 0xFF;
    if (e >= 0x7F) atomicAdd(&cnt, 1);
    __syncthreads();
    if (tid == 0) *flag = (cnt > 4) ? 1 : 0;
}

// ---------------------------------------------------------------------------
// K0b: canonicalize all 14 float tensors to fp32 in ws
// ---------------------------------------------------------------------------
struct Cvt { const void* src[14]; int off[15]; };

__global__ __launch_bounds__(256) void k_convert(Cvt c, float* __restrict__ dst,
                                                 const int* __restrict__ flag, int total)
{
    const int f = *flag;
    int i = blockIdx.x * 256 + threadIdx.x;
    if (i >= total) return;
    int t = 0;
    while (i >= c.off[t+1]) t++;
    int j = i - c.off[t];
    dst[i] = f ? ((const float*)c.src[t])[j] : bf2f(((const u16*)c.src[t])[j]);
}

// K0c: W2T[out][in] bf16 (transposed W2) for MFMA B-fragments
__global__ __launch_bounds__(256) void k_w2t(const void* __restrict__ w2src,
                                             const float* __restrict__ w2canon,
                                             u16* __restrict__ W2T,
                                             const int* __restrict__ flag)
{
    int i = blockIdx.x * 256 + threadIdx.x;
    if (i >= HID*HID) return;
    int outc = i >> 7, inc = i & 127;
    int jsrc = inc*HID + outc;
    W2T[i] = (*flag) ? f2bf(w2canon[jsrc]) : ((const u16*)w2src)[jsrc];
}

// ---------------------------------------------------------------------------
// K1: per-graph: degrees, invIn (global), layer-1 gconv via rank-1 trick,
//     write h1sT[g][c][v] = bf16( relu(t[v]*W1[c]+b1[c]) * invOut[v] ),
//     transposed + K-padded to KP (zeros for v>=200).
// ---------------------------------------------------------------------------
__global__ __launch_bounds__(256) void k_graph_l1(
    const int* __restrict__ src, const int* __restrict__ dst,
    const float* __restrict__ W1, const float* __restrict__ b1,
    float* __restrict__ invInG, u16* __restrict__ h1sT)
{
    __shared__ u16 srcL[EPG];
    __shared__ u16 dstL[EPG];
    __shared__ int degIn[NPG];
    __shared__ int degOut[NPG];
    __shared__ float sValL[NPG], sAgg[NPG], iiL[NPG], ioL[NPG], tL[NPG];
    __shared__ float w1L[HID], b1L[HID];

    const int g = blockIdx.x, tid = threadIdx.x;

    if (tid < NPG){ degIn[tid] = 0; degOut[tid] = 0; sAgg[tid] = 0.f; }
    if (tid < HID){ w1L[tid] = W1[tid]; b1L[tid] = b1[tid]; }
    __syncthreads();

    const int ebase = g * EPG;
    #pragma unroll
    for (int i = 0; i < EPG/256; i++){
        int e = i*256 + tid;
        int s = src[ebase + e] - g*NPG;
        int d = dst[ebase + e] - g*NPG;
        srcL[e] = (u16)s; dstL[e] = (u16)d;
        atomicAdd(&degOut[s], 1);
        atomicAdd(&degIn[d], 1);
    }
    __syncthreads();

    if (tid < NPG){
        int din = degIn[tid], dout = degOut[tid];
        float ii = rsqrtf(fmaxf((float)din, 1.f));
        float io = rsqrtf(fmaxf((float)dout, 1.f));
        iiL[tid] = ii; ioL[tid] = io;
        sValL[tid] = (float)din * io;          // h0 = in_deg; s = h0*inv_out
        invInG[g*NPG + tid] = ii;
    }
    __syncthreads();

    #pragma unroll
    for (int i = 0; i < EPG/256; i++){
        int e = i*256 + tid;
        atomicAdd(&sAgg[dstL[e]], sValL[srcL[e]]);
    }
    __syncthreads();

    if (tid < NPG) tL[tid] = sAgg[tid] * iiL[tid];
    __syncthreads();

    // h1sT[c][v] = bf16( relu(t[v]*w1[c]+b1[c]) * io[v] ), zero-pad v in [200,224)
    const size_t base = (size_t)g * HID * KP;
    #pragma unroll 4
    for (int i = 0; i < HID*KP/256; i++){     // 112 iters
        int idx = i*256 + tid;
        int c = idx / KP, v = idx - c*KP;
        u16 o = 0;
        if (v < NPG)
            o = f2bf(fmaxf(fmaf(tL[v], w1L[c], b1L[c]), 0.f) * ioL[v]);
        h1sT[base + idx] = o;
    }
}

// ---------------------------------------------------------------------------
// K2 (fused): per-graph dense-adjacency double-MFMA:
//   A[v][s] = edge counts (built in LDS, bf16-exact);
//   Z = A @ h1sT^T   (GEMM1, B-frags straight from global h1sT)
//   H = Z @ W2       (GEMM2, B-frags from global W2T)
//   h2 = relu(H*invIn + b2); hg = mean_v h2   (fused epilogue)
// A-frag: A[m=lr][k=quad*8+j]; B-frag: B[k=quad*8+j][n=lr]; C/D: col=lr,row=quad*4+r
// ---------------------------------------------------------------------------
__global__ __launch_bounds__(256, 1) void k_fused_graph(
    const int* __restrict__ src, const int* __restrict__ dst,
    const u16* __restrict__ h1sT, const u16* __restrict__ W2T,
    const float* __restrict__ invInG, const float* __restrict__ b2,
    float* __restrict__ hg)
{
    __shared__ __align__(16) u16 AZ[AZ_WORDS];   // dense A (208xAP), then Z (208xZP)
    __shared__ float invInL[NPG];
    __shared__ float b2L[HID];
    __shared__ float poolL[HID];

    const int g = blockIdx.x, tid = threadIdx.x;
    u32* az32 = (u32*)AZ;

    // init
    uint4* az4 = (uint4*)AZ;
    for (int i = tid; i < AZ_WORDS/8; i += 256) az4[i] = make_uint4(0,0,0,0);
    if (tid < HID){ b2L[tid] = b2[tid]; poolL[tid] = 0.f; }
    if (tid < NPG) invInL[tid] = invInG[g*NPG + tid];
    __syncthreads();

    // build A counts via u32-packed u16 atomics
    const int ebase = g * EPG;
    #pragma unroll
    for (int i = 0; i < EPG/256; i++){
        int e = ebase + i*256 + tid;
        int s = src[e] - g*NPG;
        int v = dst[e] - g*NPG;
        int idx = v*AP + s;
        atomicAdd(&az32[idx >> 1], 1u << (16*(idx & 1)));
    }
    __syncthreads();

    // convert u16 counts -> bf16 in place (counts are small ints: exact)
    for (int i = tid; i < AZ_WORDS/2; i += 256){
        u32 wv = az32[i];
        if (wv){
            u32 lo = wv & 0xFFFFu, hi = wv >> 16;
            az32[i] = (u32)f2bf((float)lo) | ((u32)f2bf((float)hi) << 16);
        }
    }
    __syncthreads();

    const int w = tid >> 6, lane = tid & 63;
    const int lr = lane & 15, quad = lane >> 4;

    f32x4 acc[4][8];
    const f32x4 fz = {0.f, 0.f, 0.f, 0.f};
    #pragma unroll
    for (int mi = 0; mi < 4; mi++)
        #pragma unroll
        for (int nt = 0; nt < 8; nt++) acc[mi][nt] = fz;

    // ---- GEMM1: Z = A(208x224) @ B,  B[k=v'][n=c] = h1sT[g][c][v']
    {
        const u16* Bg = h1sT + (size_t)g * HID * KP;
        bf16x8 bcur[8], bnxt[8];
        #pragma unroll
        for (int nt = 0; nt < 8; nt++)
            bcur[nt] = *(const bf16x8*)&Bg[(nt*16 + lr)*KP + quad*8];
        for (int ks = 0; ks < 7; ks++){
            if (ks < 6){
                #pragma unroll
                for (int nt = 0; nt < 8; nt++)
                    bnxt[nt] = *(const bf16x8*)&Bg[(nt*16 + lr)*KP + (ks+1)*32 + quad*8];
            }
            bf16x8 af[4];
            #pragma unroll
            for (int mi = 0; mi < 4; mi++){
                int mt = w + mi*4;
                if (mt < 13)
                    af[mi] = *(const bf16x8*)&AZ[(mt*16 + lr)*AP + ks*32 + quad*8];
            }
            #pragma unroll
            for (int mi = 0; mi < 4; mi++){
                int mt = w + mi*4;
                if (mt < 13){
                    #pragma unroll
                    for (int nt = 0; nt < 8; nt++)
                        acc[mi][nt] = __builtin_amdgcn_mfma_f32_16x16x32_bf16(
                            af[mi], bcur[nt], acc[mi][nt], 0, 0, 0);
                }
            }
            #pragma unroll
            for (int nt = 0; nt < 8; nt++) bcur[nt] = bnxt[nt];
        }
    }
    __syncthreads();   // all A-frag reads done; AZ now reusable for Z

    // write Z bf16 (rows 0..207 all covered by mt<13)
    #pragma unroll
    for (int mi = 0; mi < 4; mi++){
        int mt = w + mi*4;
        if (mt < 13){
            #pragma unroll
            for (int nt = 0; nt < 8; nt++){
                #pragma unroll
                for (int r = 0; r < 4; r++){
                    int v = mt*16 + quad*4 + r;
                    AZ[v*ZP + nt*16 + lr] = f2bf(acc[mi][nt][r]);
                }
            }
        }
    }
    __syncthreads();

    // ---- GEMM2: H = Z(208x128) @ W2,  B[k=cin][n=cout] = W2T[cout][cin]
    #pragma unroll
    for (int mi = 0; mi < 4; mi++)
        #pragma unroll
        for (int nt = 0; nt < 8; nt++) acc[mi][nt] = fz;
    {
        bf16x8 bcur[8], bnxt[8];
        #pragma unroll
        for (int nt = 0; nt < 8; nt++)
            bcur[nt] = *(const bf16x8*)&W2T[(nt*16 + lr)*HID + quad*8];
        for (int ks = 0; ks < 4; ks++){
            if (ks < 3){
                #pragma unroll
                for (int nt = 0; nt < 8; nt++)
                    bnxt[nt] = *(const bf16x8*)&W2T[(nt*16 + lr)*HID + (ks+1)*32 + quad*8];
            }
            bf16x8 af[4];
            #pragma unroll
            for (int mi = 0; mi < 4; mi++){
                int mt = w + mi*4;
                if (mt < 13)
                    af[mi] = *(const bf16x8*)&AZ[(mt*16 + lr)*ZP + ks*32 + quad*8];
            }
            #pragma unroll
            for (int mi = 0; mi < 4; mi++){
                int mt = w + mi*4;
                if (mt < 13){
                    #pragma unroll
                    for (int nt = 0; nt < 8; nt++)
                        acc[mi][nt] = __builtin_amdgcn_mfma_f32_16x16x32_bf16(
                            af[mi], bcur[nt], acc[mi][nt], 0, 0, 0);
                }
            }
            #pragma unroll
            for (int nt = 0; nt < 8; nt++) bcur[nt] = bnxt[nt];
        }
    }

    // epilogue: h2 = relu(acc*invIn + b2); pool += h2
    #pragma unroll
    for (int mi = 0; mi < 4; mi++){
        int mt = w + mi*4;
        if (mt < 13){
            #pragma unroll
            for (int nt = 0; nt < 8; nt++){
                int c = nt*16 + lr;
                float s = 0.f;
                #pragma unroll
                for (int r = 0; r < 4; r++){
                    int v = mt*16 + quad*4 + r;
                    if (v < NPG)
                        s += fmaxf(fmaf(acc[mi][nt][r], invInL[v], b2L[c]), 0.f);
                }
                atomicAdd(&poolL[c], s);
            }
        }
    }
    __syncthreads();
    if (tid < HID) hg[(size_t)g*HID + tid] = poolL[tid] * (1.f / NPG);
}

// ---------------------------------------------------------------------------
// MLP GEMM, split-K: P[s] = A[:, s-chunk] @ W[s-chunk, :]   (fp32)
// ---------------------------------------------------------------------------
__global__ __launch_bounds__(256) void k_mlp(
    const float* __restrict__ A, const float* __restrict__ W,
    float* __restrict__ P, int K, int Nc, int chunk)
{
    constexpr int BM = 32, BN = 64, BK = 32;
    constexpr int LA = BM*BK/256;   // 4
    constexpr int LW = BK*BN/256;   // 8
    __shared__ __align__(16) float As[2][BK][BM + 4];
    __shared__ __align__(16) float Ws[2][BK][BN + 4];

    const int row0 = blockIdx.x * BM, col0 = blockIdx.y * BN, s = blockIdx.z;
    const int k0 = s * chunk;
    const int T = chunk / BK;
    const int tid = threadIdx.x;
    const int tm = (tid >> 4) * 2;
    const int tn = (tid & 15) * 4;

    float ra[LA], rw[LW];

    #pragma unroll
    for (int i = 0; i < LA; i++){
        int idx = i*256 + tid; int r = idx >> 5, kk = idx & 31;
        ra[i] = A[(size_t)(row0 + r)*K + k0 + kk];
    }
    #pragma unroll
    for (int i = 0; i < LW; i++){
        int idx = i*256 + tid; int kk = idx >> 6, c = idx & 63;
        rw[i] = W[(size_t)(k0 + kk)*Nc + col0 + c];
    }
    #pragma unroll
    for (int i = 0; i < LA; i++){
        int idx = i*256 + tid; int r = idx >> 5, kk = idx & 31;
        As[0][kk][r] = ra[i];
    }
    #pragma unroll
    for (int i = 0; i < LW; i++){
        int idx = i*256 + tid; int kk = idx >> 6, c = idx & 63;
        Ws[0][kk][c] = rw[i];
    }
    __syncthreads();

    float acc[2][4];
    #pragma unroll
    for (int i = 0; i < 2; i++)
        #pragma unroll
        for (int j = 0; j < 4; j++) acc[i][j] = 0.f;

    for (int t = 0; t < T-1; t++){
        const int buf = t & 1, nxt = buf ^ 1;
        const int kb = k0 + (t+1)*BK;
        #pragma unroll
        for (int i = 0; i < LA; i++){
            int idx = i*256 + tid; int r = idx >> 5, kk = idx & 31;
            ra[i] = A[(size_t)(row0 + r)*K + kb + kk];
        }
        #pragma unroll
        for (int i = 0; i < LW; i++){
            int idx = i*256 + tid; int kk = idx >> 6, c = idx & 63;
            rw[i] = W[(size_t)(kb + kk)*Nc + col0 + c];
        }
        #pragma unroll
        for (int kk = 0; kk < BK; kk++){
            float2 av = *(const float2*)&As[buf][kk][tm];
            float4 bv = *(const float4*)&Ws[buf][kk][tn];
            acc[0][0] = fmaf(av.x, bv.x, acc[0][0]); acc[0][1] = fmaf(av.x, bv.y, acc[0][1]);
            acc[0][2] = fmaf(av.x, bv.z, acc[0][2]); acc[0][3] = fmaf(av.x, bv.w, acc[0][3]);
            acc[1][0] = fmaf(av.y, bv.x, acc[1][0]); acc[1][1] = fmaf(av.y, bv.y, acc[1][1]);
            acc[1][2] = fmaf(av.y, bv.z, acc[1][2]); acc[1][3] = fmaf(av.y, bv.w, acc[1][3]);
        }
        #pragma unroll
        for (int i = 0; i < LA; i++){
            int idx = i*256 + tid; int r = idx >> 5, kk = idx & 31;
            As[nxt][kk][r] = ra[i];
        }
        #pragma unroll
        for (int i = 0; i < LW; i++){
            int idx = i*256 + tid; int kk = idx >> 6, c = idx & 63;
            Ws[nxt][kk][c] = rw[i];
        }
        __syncthreads();
    }
    {
        const int buf = (T-1) & 1;
        #pragma unroll
        for (int kk = 0; kk < BK; kk++){
            float2 av = *(const float2*)&As[buf][kk][tm];
            float4 bv = *(const float4*)&Ws[buf][kk][tn];
            acc[0][0] = fmaf(av.x, bv.x, acc[0][0]); acc[0][1] = fmaf(av.x, bv.y, acc[0][1]);
            acc[0][2] = fmaf(av.x, bv.z, acc[0][2]); acc[0][3] = fmaf(av.x, bv.w, acc[0][3]);
            acc[1][0] = fmaf(av.y, bv.x, acc[1][0]); acc[1][1] = fmaf(av.y, bv.y, acc[1][1]);
            acc[1][2] = fmaf(av.y, bv.z, acc[1][2]); acc[1][3] = fmaf(av.y, bv.w, acc[1][3]);
        }
    }

    float* Pd = P + (size_t)s * ((size_t)512 * Nc);
    #pragma unroll
    for (int i = 0; i < 2; i++){
        int r = row0 + tm + i;
        float4 v = { acc[i][0], acc[i][1], acc[i][2], acc[i][3] };
        *(float4*)&Pd[(size_t)r * Nc + col0 + tn] = v;
    }
}

// Reduce S partials + bias + relu -> X (fp32)
__global__ __launch_bounds__(256) void k_reduce(
    const float* __restrict__ P, const float* __restrict__ bias,
    float* __restrict__ X, int MN, int Nc, int S)
{
    int e = blockIdx.x * 256 + threadIdx.x;
    int i0 = e * 4;
    if (i0 >= MN) return;
    float4 sum = *(const float4*)&P[i0];
    for (int s = 1; s < S; s++){
        float4 t = *(const float4*)&P[(size_t)s*MN + i0];
        sum.x += t.x; sum.y += t.y; sum.z += t.z; sum.w += t.w;
    }
    int col = i0 % Nc;
    float4 b = *(const float4*)&bias[col];
    sum.x = fmaxf(sum.x + b.x, 0.f);
    sum.y = fmaxf(sum.y + b.y, 0.f);
    sum.z = fmaxf(sum.z + b.z, 0.f);
    sum.w = fmaxf(sum.w + b.w, 0.f);
    *(float4*)&X[i0] = sum;
}

// ---------------------------------------------------------------------------
// head: logits = X4 @ We + be; softmax -> out (dtype per flag)
// ---------------------------------------------------------------------------
__global__ __launch_bounds__(64) void k_head(
    const float* __restrict__ X, const float* __restrict__ We,
    const float* __restrict__ be, void* __restrict__ out,
    const int* __restrict__ flag)
{
    const int g = blockIdx.x, lane = threadIdx.x;
    float part[10];
    #pragma unroll
    for (int c = 0; c < 10; c++) part[c] = 0.f;
    for (int k = lane; k < 512; k += 64){
        float x = X[(size_t)g*512 + k];
        #pragma unroll
        for (int c = 0; c < 10; c++) part[c] = fmaf(x, We[k*10 + c], part[c]);
    }
    #pragma unroll
    for (int c = 0; c < 10; c++){
        float v = part[c];
        for (int off = 32; off > 0; off >>= 1) v += __shfl_down(v, off);
        part[c] = v;
    }
    if (lane == 0){
        const int f = *flag;
        #pragma unroll
        for (int c = 0; c < 10; c++) part[c] += be[c];
        float m = part[0];
        #pragma unroll
        for (int c = 1; c < 10; c++) m = fmaxf(m, part[c]);
        float e[10], s = 0.f;
        #pragma unroll
        for (int c = 0; c < 10; c++){ e[c] = __expf(part[c] - m); s += e[c]; }
        float inv = 1.f / s;
        #pragma unroll
        for (int c = 0; c < 10; c++){
            float p = e[c] * inv;
            if (f) ((float*)out)[g*10 + c] = p;
            else   ((u16*)out)[g*10 + c]  = f2bf(p);
        }
    }
}

// ---------------------------------------------------------------------------
extern "C" void kernel_launch(void* const* d_in, const int* in_sizes, int n_in,
                              void* d_out, int out_size, void* d_ws, size_t ws_size,
                              hipStream_t stream)
{
    const int* src = (const int*)d_in[0];
    const int* dst = (const int*)d_in[1];

    char* ws = (char*)d_ws;
    size_t o = 0;
    int*   flag     = (int*)  (ws + o); o += 16;
    float* wcanon   = (float*)(ws + o); o += ((size_t)O_END * 4 + 15) & ~(size_t)15;
    u16*   W2T      = (u16*)  (ws + o); o += (size_t)HID * HID * 2;
    float* invIn    = (float*)(ws + o); o += (size_t)NN * 4;
    u16*   h1sT     = (u16*)  (ws + o); o += (size_t)NG * HID * KP * 2;  // 29.4 MB
    float* hg       = (float*)(ws + o); o += (size_t)NG * HID * 4;
    float* X1       = (float*)(ws + o); o += (size_t)NG * 512 * 4;
    float* X2       = (float*)(ws + o); o += (size_t)NG * 1024 * 4;
    float* X3       = (float*)(ws + o); o += (size_t)NG * 1024 * 4;
    float* X4       = (float*)(ws + o); o += (size_t)NG * 512 * 4;
    float* Pp       = (float*)h1sT;   // split-K partials alias h1sT (dead after fused)
    (void)ws_size; (void)in_sizes; (void)n_in; (void)out_size;

    k_detect<<<dim3(1), dim3(128), 0, stream>>>((const u16*)d_in[2], flag);

    Cvt cv;
    const int offs[15] = {O_W1,O_b1,O_W2,O_b2,O_Wa,O_ba,O_Wb,O_bb,O_Wc,O_bc,O_Wd,O_bd,O_We,O_be,O_END};
    for (int i = 0; i < 14; i++){ cv.src[i] = d_in[2 + i]; cv.off[i] = offs[i]; }
    cv.off[14] = offs[14];
    k_convert<<<dim3((O_END + 255)/256), dim3(256), 0, stream>>>(cv, wcanon, flag, O_END);
    k_w2t<<<dim3((HID*HID + 255)/256), dim3(256), 0, stream>>>(d_in[4], wcanon + O_W2, W2T, flag);

    const float *W1 = wcanon+O_W1, *b1 = wcanon+O_b1, *b2 = wcanon+O_b2;
    const float *Wa = wcanon+O_Wa, *ba = wcanon+O_ba, *Wb = wcanon+O_Wb, *bb = wcanon+O_bb;
    const float *Wc = wcanon+O_Wc, *bc = wcanon+O_bc, *Wd = wcanon+O_Wd, *bd = wcanon+O_bd;
    const float *We = wcanon+O_We, *be = wcanon+O_be;

    // K1: degrees + layer1 (writes h1sT transposed, inv_out folded in)
    k_graph_l1<<<dim3(NG), dim3(256), 0, stream>>>(
        src, dst, W1, b1, invIn, h1sT);

    // K2 fused: dense-A MFMA x2 + pooling -> hg
    k_fused_graph<<<dim3(NG), dim3(256), 0, stream>>>(
        src, dst, h1sT, W2T, invIn, b2, hg);

    // MLP: split-K GEMM + reduce(bias+relu)
    k_mlp<<<dim3(16, 8, 2),  dim3(256), 0, stream>>>(hg, Wa, Pp, 128, 512, 64);
    k_reduce<<<dim3(512*512/1024), dim3(256), 0, stream>>>(Pp, ba, X1, 512*512, 512, 2);
    k_mlp<<<dim3(16, 16, 4), dim3(256), 0, stream>>>(X1, Wb, Pp, 512, 1024, 128);
    k_reduce<<<dim3(512*1024/1024), dim3(256), 0, stream>>>(Pp, bb, X2, 512*1024, 1024, 4);
    k_mlp<<<dim3(16, 16, 4), dim3(256), 0, stream>>>(X2, Wc, Pp, 1024, 1024, 256);
    k_reduce<<<dim3(512*1024/1024), dim3(256), 0, stream>>>(Pp, bc, X3, 512*1024, 1024, 4);
    k_mlp<<<dim3(16, 8, 4),  dim3(256), 0, stream>>>(X3, Wd, Pp, 1024, 512, 256);
    k_reduce<<<dim3(512*512/1024), dim3(256), 0, stream>>>(Pp, bd, X4, 512*512, 512, 4);

    // head + softmax
    k_head<<<dim3(NG), dim3(64), 0, stream>>>(X4, We, be, d_out, flag);
}

// Round 5
// 293.170 us; speedup vs baseline: 2.3529x; 1.0220x over previous
//
#include <hip/hip_runtime.h>
#include <stdint.h>

typedef unsigned short u16;
typedef unsigned int   u32;

#define NG   512
#define NPG  200
#define EPG  6400
#define NN   (NG*NPG)     // 102400 nodes
#define NE_  (NG*EPG)     // 3276800 edges
#define HID  128
#define KP   224          // padded src-dim (K) for GEMM1, multiple of 32
#define AP   232          // dense-A row stride in u16 (16B-aligned, conflict-breaking)
#define ZP   136          // Z row stride in u16 (16B-aligned)
#define RQ   64           // padded dst-rows per quarter block (50 used)
#define QCAP 2048         // edge-bucket capacity per (graph, quarter)

__device__ __forceinline__ float bf2f(u16 b){ u32 u = ((u32)b) << 16; return __builtin_bit_cast(float, u); }
__device__ __forceinline__ u16 f2bf(float f){
    u32 u = __builtin_bit_cast(u32, f);
    u = (u + 0x7FFFu + ((u >> 16) & 1u)) >> 16;
    return (u16)u;
}

typedef __attribute__((ext_vector_type(8))) short bf16x8;
typedef __attribute__((ext_vector_type(4))) float f32x4;

// Canonical fp32 weight-region element offsets
enum : int {
  O_W1 = 0,        O_b1 = 128,      O_W2 = 256,      O_b2 = 16640,
  O_Wa = 16768,    O_ba = 82304,    O_Wb = 82816,    O_bb = 607104,
  O_Wc = 608128,   O_bc = 1656704,  O_Wd = 1657728,  O_bd = 2182016,
  O_We = 2182528,  O_be = 2187648,  O_END = 2187658
};

// ---------------------------------------------------------------------------
// K0a: dtype detector (1 = fp32 inputs, 0 = bf16 inputs)
// ---------------------------------------------------------------------------
__global__ __launch_bounds__(128) void k_detect(const u16* __restrict__ w1bits,
                                                int* __restrict__ flag)
{
    __shared__ int cnt;
    const int tid = threadIdx.x;
    if (tid == 0) cnt = 0;
    __syncthreads();
    u16 u = w1bits[tid];
    int e = (u >> 7) & 0xFF;
    if (e >= 0x7F) atomicAdd(&cnt, 1);
    __syncthreads();
    if (tid == 0) *flag = (cnt > 4) ? 1 : 0;
}

// ---------------------------------------------------------------------------
// K0b: canonicalize all 14 float tensors to fp32 in ws
// ---------------------------------------------------------------------------
struct Cvt { const void* src[14]; int off[15]; };

__global__ __launch_bounds__(256) void k_convert(Cvt c, float* __restrict__ dst,
                                                 const int* __restrict__ flag, int total)
{
    const int f = *flag;
    int i = blockIdx.x * 256 + threadIdx.x;
    if (i >= total) return;
    int t = 0;
    while (i >= c.off[t+1]) t++;
    int j = i - c.off[t];
    dst[i] = f ? ((const float*)c.src[t])[j] : bf2f(((const u16*)c.src[t])[j]);
}

// K0c: W2T[out][in] bf16 (transposed W2) for MFMA B-fragments; also zero hg.
__global__ __launch_bounds__(256) void k_w2t(const void* __restrict__ w2src,
                                             const float* __restrict__ w2canon,
                                             u16* __restrict__ W2T,
                                             float* __restrict__ hg,
                                             const int* __restrict__ flag)
{
    int i = blockIdx.x * 256 + threadIdx.x;
    if (i < HID*HID){
        int outc = i >> 7, inc = i & 127;
        int jsrc = inc*HID + outc;
        W2T[i] = (*flag) ? f2bf(w2canon[jsrc]) : ((const u16*)w2src)[jsrc];
    }
    // zero hg (NG*HID = 65536 floats, grid = 64 blocks -> 1024 per block)
    #pragma unroll
    for (int k = 0; k < 4; k++){
        int j = blockIdx.x * 1024 + k*256 + threadIdx.x;
        if (j < NG*HID) hg[j] = 0.f;
    }
}

// ---------------------------------------------------------------------------
// K1: per-graph: degrees, invIn, layer-1 gconv (rank-1 trick),
//     h1sT[g][c][v] = bf16(relu(t[v]*W1[c]+b1[c]) * invOut[v]), K-padded;
//     PLUS: bucket-scatter edges by dst-quarter -> edgeBuf/cntQ for K2.
// ---------------------------------------------------------------------------
__global__ __launch_bounds__(256) void k_graph_l1(
    const int* __restrict__ src, const int* __restrict__ dst,
    const float* __restrict__ W1, const float* __restrict__ b1,
    float* __restrict__ invInG, u16* __restrict__ h1sT,
    u32* __restrict__ edgeBuf, int* __restrict__ cntQ)
{
    __shared__ u16 srcL[EPG];
    __shared__ u16 dstL[EPG];
    __shared__ int degIn[NPG];
    __shared__ int degOut[NPG];
    __shared__ int qcur[4];
    __shared__ float sValL[NPG], sAgg[NPG], iiL[NPG], ioL[NPG], tL[NPG];
    __shared__ float w1L[HID], b1L[HID];

    const int g = blockIdx.x, tid = threadIdx.x;

    if (tid < NPG){ degIn[tid] = 0; degOut[tid] = 0; sAgg[tid] = 0.f; }
    if (tid < HID){ w1L[tid] = W1[tid]; b1L[tid] = b1[tid]; }
    if (tid < 4) qcur[tid] = 0;
    __syncthreads();

    const int ebase = g * EPG;
    #pragma unroll
    for (int i = 0; i < EPG/256; i++){
        int e = i*256 + tid;
        int s = src[ebase + e] - g*NPG;
        int d = dst[ebase + e] - g*NPG;
        srcL[e] = (u16)s; dstL[e] = (u16)d;
        atomicAdd(&degOut[s], 1);
        atomicAdd(&degIn[d], 1);
    }
    __syncthreads();

    if (tid < NPG){
        int din = degIn[tid], dout = degOut[tid];
        float ii = rsqrtf(fmaxf((float)din, 1.f));
        float io = rsqrtf(fmaxf((float)dout, 1.f));
        iiL[tid] = ii; ioL[tid] = io;
        sValL[tid] = (float)din * io;          // h0 = in_deg; s = h0*inv_out
        invInG[g*NPG + tid] = ii;
    }
    __syncthreads();

    // layer-1 scalar aggregation + bucket scatter (q = d/50 via mul-shift)
    #pragma unroll
    for (int i = 0; i < EPG/256; i++){
        int e = i*256 + tid;
        int s = srcL[e], d = dstL[e];
        atomicAdd(&sAgg[d], sValL[s]);
        int q = (d * 41) >> 11;                // exact d/50 for d in [0,200)
        int pos = atomicAdd(&qcur[q], 1);
        if (pos < QCAP)
            edgeBuf[((size_t)(g*4 + q))*QCAP + pos] = (u32)s | ((u32)(d - q*50) << 16);
    }
    __syncthreads();

    if (tid < 4) cntQ[g*4 + tid] = (qcur[tid] < QCAP) ? qcur[tid] : QCAP;
    if (tid < NPG) tL[tid] = sAgg[tid] * iiL[tid];
    __syncthreads();

    // h1sT[c][v] = bf16( relu(t[v]*w1[c]+b1[c]) * io[v] ), zero-pad v in [200,224)
    const size_t base = (size_t)g * HID * KP;
    #pragma unroll 4
    for (int i = 0; i < HID*KP/256; i++){
        int idx = i*256 + tid;
        int c = idx / KP, v = idx - c*KP;
        u16 o = 0;
        if (v < NPG)
            o = f2bf(fmaxf(fmaf(tL[v], w1L[c], b1L[c]), 0.f) * ioL[v]);
        h1sT[base + idx] = o;
    }
}

// ---------------------------------------------------------------------------
// K2 (fused, quarter-split): block = (graph g, dst-quarter q), 50 rows.
//   A[dl][s] edge counts built in 29.7KB LDS from pre-bucketed edges;
//   Z = A @ h1s^T; H = Z @ W2; h2 = relu(H*invIn + b2); hg += sum_v h2.
// Waves tiled 2m x 2n (each wave: 2 m-tiles, 64 cols).
// A-frag: A[m=lr][k=quad*8+j]; B-frag: B[k=quad*8+j][n=lr]; C/D: col=lr,row=quad*4+r
// ---------------------------------------------------------------------------
__global__ __launch_bounds__(256, 4) void k_fused_graph(
    const u32* __restrict__ edgeBuf, const int* __restrict__ cntQ,
    const u16* __restrict__ h1sT, const u16* __restrict__ W2T,
    const float* __restrict__ invInG, const float* __restrict__ b2,
    float* __restrict__ hg)
{
    __shared__ __align__(16) u16 AZ[RQ*AP];   // 29.7 KB: dense A, then Z (64xZP)
    __shared__ float invInL[RQ];
    __shared__ float b2L[HID];
    __shared__ float poolL[HID];

    const int bid = blockIdx.x, tid = threadIdx.x;
    const int g = bid >> 2, q = bid & 3;
    u32* az32 = (u32*)AZ;
    uint4* az4 = (uint4*)AZ;

    #pragma unroll
    for (int i = 0; i < 8; i++){
        int idx = i*256 + tid;
        if (idx < RQ*AP/8) az4[idx] = make_uint4(0,0,0,0);
    }
    if (tid < HID){ b2L[tid] = b2[tid]; poolL[tid] = 0.f; }
    if (tid < RQ) invInL[tid] = (tid < 50) ? invInG[g*NPG + q*50 + tid] : 0.f;
    __syncthreads();

    // build A counts from this block's bucket (u32-packed u16 atomics)
    const int cnt = cntQ[bid];
    const u32* eb = edgeBuf + (size_t)bid * QCAP;
    for (int i = tid; i < cnt; i += 256){
        u32 e = eb[i];
        int s = e & 0xFFFF, dl = e >> 16;
        int idx = dl*AP + s;
        atomicAdd(&az32[idx >> 1], 1u << (16*(idx & 1)));
    }
    __syncthreads();

    // u16 counts -> bf16 in place (small ints: exact)
    for (int i = tid; i < RQ*AP/2; i += 256){
        u32 wv = az32[i];
        if (wv)
            az32[i] = (u32)f2bf((float)(wv & 0xFFFFu)) | ((u32)f2bf((float)(wv >> 16)) << 16);
    }
    __syncthreads();

    const int w = tid >> 6, lane = tid & 63;
    const int wm = w >> 1, wn = w & 1;
    const int lr = lane & 15, quad = lane >> 4;

    f32x4 acc[2][4];
    const f32x4 fz = {0.f, 0.f, 0.f, 0.f};
    #pragma unroll
    for (int mi = 0; mi < 2; mi++)
        #pragma unroll
        for (int nt = 0; nt < 4; nt++) acc[mi][nt] = fz;

    // ---- GEMM1: Z = A(64x224) @ B, B[k=v'][n=c] = h1sT[g][c][v'], cols wn*64..+63
    {
        const u16* Bg = h1sT + (size_t)g * HID * KP + (size_t)(wn*64) * KP;
        bf16x8 bcur[4], bnxt[4];
        #pragma unroll
        for (int nt = 0; nt < 4; nt++)
            bcur[nt] = *(const bf16x8*)&Bg[(nt*16 + lr)*KP + quad*8];
        for (int ks = 0; ks < 7; ks++){
            if (ks < 6){
                #pragma unroll
                for (int nt = 0; nt < 4; nt++)
                    bnxt[nt] = *(const bf16x8*)&Bg[(nt*16 + lr)*KP + (ks+1)*32 + quad*8];
            }
            bf16x8 af[2];
            #pragma unroll
            for (int mi = 0; mi < 2; mi++)
                af[mi] = *(const bf16x8*)&AZ[((wm*2 + mi)*16 + lr)*AP + ks*32 + quad*8];
            #pragma unroll
            for (int mi = 0; mi < 2; mi++)
                #pragma unroll
                for (int nt = 0; nt < 4; nt++)
                    acc[mi][nt] = __builtin_amdgcn_mfma_f32_16x16x32_bf16(
                        af[mi], bcur[nt], acc[mi][nt], 0, 0, 0);
            #pragma unroll
            for (int nt = 0; nt < 4; nt++) bcur[nt] = bnxt[nt];
        }
    }
    __syncthreads();   // all A reads done; AZ now holds Z

    // write Z bf16 into AZ (64 x ZP)
    #pragma unroll
    for (int mi = 0; mi < 2; mi++)
        #pragma unroll
        for (int nt = 0; nt < 4; nt++)
            #pragma unroll
            for (int r = 0; r < 4; r++){
                int v = (wm*2 + mi)*16 + quad*4 + r;
                int c = wn*64 + nt*16 + lr;
                AZ[v*ZP + c] = f2bf(acc[mi][nt][r]);
            }
    __syncthreads();

    // ---- GEMM2: H = Z(64x128) @ W2, B[k=cin][n=cout] = W2T[cout][cin]
    #pragma unroll
    for (int mi = 0; mi < 2; mi++)
        #pragma unroll
        for (int nt = 0; nt < 4; nt++) acc[mi][nt] = fz;
    {
        const u16* Wg = W2T + (size_t)(wn*64) * HID;
        bf16x8 bcur[4], bnxt[4];
        #pragma unroll
        for (int nt = 0; nt < 4; nt++)
            bcur[nt] = *(const bf16x8*)&Wg[(nt*16 + lr)*HID + quad*8];
        for (int ks = 0; ks < 4; ks++){
            if (ks < 3){
                #pragma unroll
                for (int nt = 0; nt < 4; nt++)
                    bnxt[nt] = *(const bf16x8*)&Wg[(nt*16 + lr)*HID + (ks+1)*32 + quad*8];
            }
            bf16x8 af[2];
            #pragma unroll
            for (int mi = 0; mi < 2; mi++)
                af[mi] = *(const bf16x8*)&AZ[((wm*2 + mi)*16 + lr)*ZP + ks*32 + quad*8];
            #pragma unroll
            for (int mi = 0; mi < 2; mi++)
                #pragma unroll
                for (int nt = 0; nt < 4; nt++)
                    acc[mi][nt] = __builtin_amdgcn_mfma_f32_16x16x32_bf16(
                        af[mi], bcur[nt], acc[mi][nt], 0, 0, 0);
            #pragma unroll
            for (int nt = 0; nt < 4; nt++) bcur[nt] = bnxt[nt];
        }
    }

    // epilogue: h2 = relu(acc*invIn + b2); pool; global accumulate
    #pragma unroll
    for (int mi = 0; mi < 2; mi++)
        #pragma unroll
        for (int nt = 0; nt < 4; nt++){
            int c = wn*64 + nt*16 + lr;
            float s = 0.f;
            #pragma unroll
            for (int r = 0; r < 4; r++){
                int v = (wm*2 + mi)*16 + quad*4 + r;
                if (v < 50)
                    s += fmaxf(fmaf(acc[mi][nt][r], invInL[v], b2L[c]), 0.f);
            }
            atomicAdd(&poolL[c], s);
        }
    __syncthreads();
    if (tid < HID) atomicAdd(&hg[(size_t)g*HID + tid], poolL[tid] * (1.f / NPG));
}

// ---------------------------------------------------------------------------
// MLP GEMM, split-K: P[s] = A[:, s-chunk] @ W[s-chunk, :]   (fp32)
// ---------------------------------------------------------------------------
__global__ __launch_bounds__(256) void k_mlp(
    const float* __restrict__ A, const float* __restrict__ W,
    float* __restrict__ P, int K, int Nc, int chunk)
{
    constexpr int BM = 32, BN = 64, BK = 32;
    constexpr int LA = BM*BK/256;   // 4
    constexpr int LW = BK*BN/256;   // 8
    __shared__ __align__(16) float As[2][BK][BM + 4];
    __shared__ __align__(16) float Ws[2][BK][BN + 4];

    const int row0 = blockIdx.x * BM, col0 = blockIdx.y * BN, s = blockIdx.z;
    const int k0 = s * chunk;
    const int T = chunk / BK;
    const int tid = threadIdx.x;
    const int tm = (tid >> 4) * 2;
    const int tn = (tid & 15) * 4;

    float ra[LA], rw[LW];

    #pragma unroll
    for (int i = 0; i < LA; i++){
        int idx = i*256 + tid; int r = idx >> 5, kk = idx & 31;
        ra[i] = A[(size_t)(row0 + r)*K + k0 + kk];
    }
    #pragma unroll
    for (int i = 0; i < LW; i++){
        int idx = i*256 + tid; int kk = idx >> 6, c = idx & 63;
        rw[i] = W[(size_t)(k0 + kk)*Nc + col0 + c];
    }
    #pragma unroll
    for (int i = 0; i < LA; i++){
        int idx = i*256 + tid; int r = idx >> 5, kk = idx & 31;
        As[0][kk][r] = ra[i];
    }
    #pragma unroll
    for (int i = 0; i < LW; i++){
        int idx = i*256 + tid; int kk = idx >> 6, c = idx & 63;
        Ws[0][kk][c] = rw[i];
    }
    __syncthreads();

    float acc[2][4];
    #pragma unroll
    for (int i = 0; i < 2; i++)
        #pragma unroll
        for (int j = 0; j < 4; j++) acc[i][j] = 0.f;

    for (int t = 0; t < T-1; t++){
        const int buf = t & 1, nxt = buf ^ 1;
        const int kb = k0 + (t+1)*BK;
        #pragma unroll
        for (int i = 0; i < LA; i++){
            int idx = i*256 + tid; int r = idx >> 5, kk = idx & 31;
            ra[i] = A[(size_t)(row0 + r)*K + kb + kk];
        }
        #pragma unroll
        for (int i = 0; i < LW; i++){
            int idx = i*256 + tid; int kk = idx >> 6, c = idx & 63;
            rw[i] = W[(size_t)(kb + kk)*Nc + col0 + c];
        }
        #pragma unroll
        for (int kk = 0; kk < BK; kk++){
            float2 av = *(const float2*)&As[buf][kk][tm];
            float4 bv = *(const float4*)&Ws[buf][kk][tn];
            acc[0][0] = fmaf(av.x, bv.x, acc[0][0]); acc[0][1] = fmaf(av.x, bv.y, acc[0][1]);
            acc[0][2] = fmaf(av.x, bv.z, acc[0][2]); acc[0][3] = fmaf(av.x, bv.w, acc[0][3]);
            acc[1][0] = fmaf(av.y, bv.x, acc[1][0]); acc[1][1] = fmaf(av.y, bv.y, acc[1][1]);
            acc[1][2] = fmaf(av.y, bv.z, acc[1][2]); acc[1][3] = fmaf(av.y, bv.w, acc[1][3]);
        }
        #pragma unroll
        for (int i = 0; i < LA; i++){
            int idx = i*256 + tid; int r = idx >> 5, kk = idx & 31;
            As[nxt][kk][r] = ra[i];
        }
        #pragma unroll
        for (int i = 0; i < LW; i++){
            int idx = i*256 + tid; int kk = idx >> 6, c = idx & 63;
            Ws[nxt][kk][c] = rw[i];
        }
        __syncthreads();
    }
    {
        const int buf = (T-1) & 1;
        #pragma unroll
        for (int kk = 0; kk < BK; kk++){
            float2 av = *(const float2*)&As[buf][kk][tm];
            float4 bv = *(const float4*)&Ws[buf][kk][tn];
            acc[0][0] = fmaf(av.x, bv.x, acc[0][0]); acc[0][1] = fmaf(av.x, bv.y, acc[0][1]);
            acc[0][2] = fmaf(av.x, bv.z, acc[0][2]); acc[0][3] = fmaf(av.x, bv.w, acc[0][3]);
            acc[1][0] = fmaf(av.y, bv.x, acc[1][0]); acc[1][1] = fmaf(av.y, bv.y, acc[1][1]);
            acc[1][2] = fmaf(av.y, bv.z, acc[1][2]); acc[1][3] = fmaf(av.y, bv.w, acc[1][3]);
        }
    }

    float* Pd = P + (size_t)s * ((size_t)512 * Nc);
    #pragma unroll
    for (int i = 0; i < 2; i++){
        int r = row0 + tm + i;
        float4 v = { acc[i][0], acc[i][1], acc[i][2], acc[i][3] };
        *(float4*)&Pd[(size_t)r * Nc + col0 + tn] = v;
    }
}

// Reduce S partials + bias + relu -> X (fp32)
__global__ __launch_bounds__(256) void k_reduce(
    const float* __restrict__ P, const float* __restrict__ bias,
    float* __restrict__ X, int MN, int Nc, int S)
{
    int e = blockIdx.x * 256 + threadIdx.x;
    int i0 = e * 4;
    if (i0 >= MN) return;
    float4 sum = *(const float4*)&P[i0];
    for (int s = 1; s < S; s++){
        float4 t = *(const float4*)&P[(size_t)s*MN + i0];
        sum.x += t.x; sum.y += t.y; sum.z += t.z; sum.w += t.w;
    }
    int col = i0 % Nc;
    float4 b = *(const float4*)&bias[col];
    sum.x = fmaxf(sum.x + b.x, 0.f);
    sum.y = fmaxf(sum.y + b.y, 0.f);
    sum.z = fmaxf(sum.z + b.z, 0.f);
    sum.w = fmaxf(sum.w + b.w, 0.f);
    *(float4*)&X[i0] = sum;
}

// ---------------------------------------------------------------------------
// head: logits = X4 @ We + be; softmax -> out (dtype per flag)
// ---------------------------------------------------------------------------
__global__ __launch_bounds__(64) void k_head(
    const float* __restrict__ X, const float* __restrict__ We,
    const float* __restrict__ be, void* __restrict__ out,
    const int* __restrict__ flag)
{
    const int g = blockIdx.x, lane = threadIdx.x;
    float part[10];
    #pragma unroll
    for (int c = 0; c < 10; c++) part[c] = 0.f;
    for (int k = lane; k < 512; k += 64){
        float x = X[(size_t)g*512 + k];
        #pragma unroll
        for (int c = 0; c < 10; c++) part[c] = fmaf(x, We[k*10 + c], part[c]);
    }
    #pragma unroll
    for (int c = 0; c < 10; c++){
        float v = part[c];
        for (int off = 32; off > 0; off >>= 1) v += __shfl_down(v, off);
        part[c] = v;
    }
    if (lane == 0){
        const int f = *flag;
        #pragma unroll
        for (int c = 0; c < 10; c++) part[c] += be[c];
        float m = part[0];
        #pragma unroll
        for (int c = 1; c < 10; c++) m = fmaxf(m, part[c]);
        float e[10], s = 0.f;
        #pragma unroll
        for (int c = 0; c < 10; c++){ e[c] = __expf(part[c] - m); s += e[c]; }
        float inv = 1.f / s;
        #pragma unroll
        for (int c = 0; c < 10; c++){
            float p = e[c] * inv;
            if (f) ((float*)out)[g*10 + c] = p;
            else   ((u16*)out)[g*10 + c]  = f2bf(p);
        }
    }
}

// ---------------------------------------------------------------------------
extern "C" void kernel_launch(void* const* d_in, const int* in_sizes, int n_in,
                              void* d_out, int out_size, void* d_ws, size_t ws_size,
                              hipStream_t stream)
{
    const int* src = (const int*)d_in[0];
    const int* dst = (const int*)d_in[1];

    char* ws = (char*)d_ws;
    size_t o = 0;
    int*   flag     = (int*)  (ws + o); o += 16;
    float* wcanon   = (float*)(ws + o); o += ((size_t)O_END * 4 + 15) & ~(size_t)15;
    u16*   W2T      = (u16*)  (ws + o); o += (size_t)HID * HID * 2;
    float* invIn    = (float*)(ws + o); o += (size_t)NN * 4;
    u32*   edgeBuf  = (u32*)  (ws + o); o += (size_t)NG * 4 * QCAP * 4;   // 16.8 MB
    int*   cntQ     = (int*)  (ws + o); o += (size_t)NG * 4 * 4;
    u16*   h1sT     = (u16*)  (ws + o); o += (size_t)NG * HID * KP * 2;   // 29.4 MB
    float* hg       = (float*)(ws + o); o += (size_t)NG * HID * 4;
    float* X1       = (float*)(ws + o); o += (size_t)NG * 512 * 4;
    float* X2       = (float*)(ws + o); o += (size_t)NG * 1024 * 4;
    float* X3       = (float*)(ws + o); o += (size_t)NG * 1024 * 4;
    float* X4       = (float*)(ws + o); o += (size_t)NG * 512 * 4;
    float* Pp       = (float*)h1sT;   // split-K partials alias h1sT (dead after fused)
    (void)ws_size; (void)in_sizes; (void)n_in; (void)out_size;

    k_detect<<<dim3(1), dim3(128), 0, stream>>>((const u16*)d_in[2], flag);

    Cvt cv;
    const int offs[15] = {O_W1,O_b1,O_W2,O_b2,O_Wa,O_ba,O_Wb,O_bb,O_Wc,O_bc,O_Wd,O_bd,O_We,O_be,O_END};
    for (int i = 0; i < 14; i++){ cv.src[i] = d_in[2 + i]; cv.off[i] = offs[i]; }
    cv.off[14] = offs[14];
    k_convert<<<dim3((O_END + 255)/256), dim3(256), 0, stream>>>(cv, wcanon, flag, O_END);
    k_w2t<<<dim3(64), dim3(256), 0, stream>>>(d_in[4], wcanon + O_W2, W2T, hg, flag);

    const float *W1 = wcanon+O_W1, *b1 = wcanon+O_b1, *b2 = wcanon+O_b2;
    const float *Wa = wcanon+O_Wa, *ba = wcanon+O_ba, *Wb = wcanon+O_Wb, *bb = wcanon+O_bb;
    const float *Wc = wcanon+O_Wc, *bc = wcanon+O_bc, *Wd = wcanon+O_Wd, *bd = wcanon+O_bd;
    const float *We = wcanon+O_We, *be = wcanon+O_be;

    // K1: degrees + layer1 + edge bucketing
    k_graph_l1<<<dim3(NG), dim3(256), 0, stream>>>(
        src, dst, W1, b1, invIn, h1sT, edgeBuf, cntQ);

    // K2 fused: quarter-split dense-A MFMA x2 + pooling -> hg (2048 blocks)
    k_fused_graph<<<dim3(NG*4), dim3(256), 0, stream>>>(
        edgeBuf, cntQ, h1sT, W2T, invIn, b2, hg);

    // MLP: split-K GEMM + reduce(bias+relu)
    k_mlp<<<dim3(16, 8, 2),  dim3(256), 0, stream>>>(hg, Wa, Pp, 128, 512, 64);
    k_reduce<<<dim3(512*512/1024), dim3(256), 0, stream>>>(Pp, ba, X1, 512*512, 512, 2);
    k_mlp<<<dim3(16, 16, 4), dim3(256), 0, stream>>>(X1, Wb, Pp, 512, 1024, 128);
    k_reduce<<<dim3(512*1024/1024), dim3(256), 0, stream>>>(Pp, bb, X2, 512*1024, 1024, 4);
    k_mlp<<<dim3(16, 16, 4), dim3(256), 0, stream>>>(X2, Wc, Pp, 1024, 1024, 256);
    k_reduce<<<dim3(512*1024/1024), dim3(256), 0, stream>>>(Pp, bc, X3, 512*1024, 1024, 4);
    k_mlp<<<dim3(16, 8, 4),  dim3(256), 0, stream>>>(X3, Wd, Pp, 1024, 512, 256);
    k_reduce<<<dim3(512*512/1024), dim3(256), 0, stream>>>(Pp, bd, X4, 512*512, 512, 4);

    // head + softmax
    k_head<<<dim3(NG), dim3(64), 0, stream>>>(X4, We, be, d_out, flag);
}

// Round 6
// 278.753 us; speedup vs baseline: 2.4745x; 1.0517x over previous
//
#include <hip/hip_runtime.h>
#include <stdint.h>

typedef unsigned short u16;
typedef unsigned int   u32;

#define NG   512
#define NPG  200
#define EPG  6400
#define NN   (NG*NPG)     // 102400 nodes
#define NE_  (NG*EPG)     // 3276800 edges
#define HID  128
#define KP   224          // padded src-dim (K) for GEMM1, multiple of 32
#define AP   232          // dense-A row stride in u16 (16B-aligned, conflict-breaking)
#define ZP   136          // Z row stride in u16 (16B-aligned)
#define RQ   64           // padded dst-rows per quarter block (50 used)
#define QCAP 2048         // edge-bucket capacity per (graph, quarter)

__device__ __forceinline__ float bf2f(u16 b){ u32 u = ((u32)b) << 16; return __builtin_bit_cast(float, u); }
__device__ __forceinline__ u16 f2bf(float f){
    u32 u = __builtin_bit_cast(u32, f);
    u = (u + 0x7FFFu + ((u >> 16) & 1u)) >> 16;
    return (u16)u;
}

typedef __attribute__((ext_vector_type(8))) short bf16x8;
typedef __attribute__((ext_vector_type(4))) float f32x4;

// Canonical fp32 weight-region element offsets
enum : int {
  O_W1 = 0,        O_b1 = 128,      O_W2 = 256,      O_b2 = 16640,
  O_Wa = 16768,    O_ba = 82304,    O_Wb = 82816,    O_bb = 607104,
  O_Wc = 608128,   O_bc = 1656704,  O_Wd = 1657728,  O_bd = 2182016,
  O_We = 2182528,  O_be = 2187648,  O_END = 2187658
};

// Transposed-weight arena element offsets (bf16, [n][k] layout)
enum : int {
  T_Wa = 0,                       // 512 x 128
  T_Wb = 65536,                   // 1024 x 512
  T_Wc = 65536 + 524288,          // 1024 x 1024
  T_Wd = 65536 + 524288 + 1048576,// 512 x 1024
  T_END = 65536 + 524288 + 1048576 + 524288
};

// ---------------------------------------------------------------------------
// K0a: dtype detector (1 = fp32 inputs, 0 = bf16 inputs)
// ---------------------------------------------------------------------------
__global__ __launch_bounds__(128) void k_detect(const u16* __restrict__ w1bits,
                                                int* __restrict__ flag)
{
    __shared__ int cnt;
    const int tid = threadIdx.x;
    if (tid == 0) cnt = 0;
    __syncthreads();
    u16 u = w1bits[tid];
    int e = (u >> 7) & 0xFF;
    if (e >= 0x7F) atomicAdd(&cnt, 1);
    __syncthreads();
    if (tid == 0) *flag = (cnt > 4) ? 1 : 0;
}

// ---------------------------------------------------------------------------
// K0b: canonicalize all 14 float tensors to fp32 in ws
// ---------------------------------------------------------------------------
struct Cvt { const void* src[14]; int off[15]; };

__global__ __launch_bounds__(256) void k_convert(Cvt c, float* __restrict__ dst,
                                                 const int* __restrict__ flag, int total)
{
    const int f = *flag;
    int i = blockIdx.x * 256 + threadIdx.x;
    if (i >= total) return;
    int t = 0;
    while (i >= c.off[t+1]) t++;
    int j = i - c.off[t];
    dst[i] = f ? ((const float*)c.src[t])[j] : bf2f(((const u16*)c.src[t])[j]);
}

// K0c: W2T[out][in] bf16 (transposed W2) for MFMA B-fragments; also zero hg.
__global__ __launch_bounds__(256) void k_w2t(const void* __restrict__ w2src,
                                             const float* __restrict__ w2canon,
                                             u16* __restrict__ W2T,
                                             float* __restrict__ hg,
                                             const int* __restrict__ flag)
{
    int i = blockIdx.x * 256 + threadIdx.x;
    if (i < HID*HID){
        int outc = i >> 7, inc = i & 127;
        int jsrc = inc*HID + outc;
        W2T[i] = (*flag) ? f2bf(w2canon[jsrc]) : ((const u16*)w2src)[jsrc];
    }
    #pragma unroll
    for (int k = 0; k < 4; k++){
        int j = blockIdx.x * 1024 + k*256 + threadIdx.x;
        if (j < NG*HID) hg[j] = 0.f;
    }
}

// ---------------------------------------------------------------------------
// K0d: transpose the 4 MLP weights into n-major bf16 arena (WT[n][k]).
// All K are powers of two -> shift/mask index math.
// ---------------------------------------------------------------------------
struct TD { const void* src; int coff; int logK; int N; int dst0; int dst1; };
struct TD4 { TD t[4]; };

__global__ __launch_bounds__(256) void k_wt(TD4 d, const float* __restrict__ canon,
                                            u16* __restrict__ dst,
                                            const int* __restrict__ flag, int total)
{
    const int f = *flag;
    int i = blockIdx.x * 256 + threadIdx.x;
    if (i >= total) return;
    int t = 0;
    while (i >= d.t[t].dst1) t++;
    const TD& td = d.t[t];
    int j = i - td.dst0;
    int n = j >> td.logK;
    int k = j & ((1 << td.logK) - 1);
    int srcidx = k * td.N + n;
    dst[i] = f ? f2bf(canon[td.coff + srcidx]) : ((const u16*)td.src)[srcidx];
}

// ---------------------------------------------------------------------------
// K1: per-graph: degrees, invIn, layer-1 gconv (rank-1 trick),
//     h1sT[g][c][v] = bf16(relu(t[v]*W1[c]+b1[c]) * invOut[v]), K-padded;
//     PLUS: bucket-scatter edges by dst-quarter -> edgeBuf/cntQ for K2.
// ---------------------------------------------------------------------------
__global__ __launch_bounds__(256) void k_graph_l1(
    const int* __restrict__ src, const int* __restrict__ dst,
    const float* __restrict__ W1, const float* __restrict__ b1,
    float* __restrict__ invInG, u16* __restrict__ h1sT,
    u32* __restrict__ edgeBuf, int* __restrict__ cntQ)
{
    __shared__ u16 srcL[EPG];
    __shared__ u16 dstL[EPG];
    __shared__ int degIn[NPG];
    __shared__ int degOut[NPG];
    __shared__ int qcur[4];
    __shared__ float sValL[NPG], sAgg[NPG], iiL[NPG], ioL[NPG], tL[NPG];
    __shared__ float w1L[HID], b1L[HID];

    const int g = blockIdx.x, tid = threadIdx.x;

    if (tid < NPG){ degIn[tid] = 0; degOut[tid] = 0; sAgg[tid] = 0.f; }
    if (tid < HID){ w1L[tid] = W1[tid]; b1L[tid] = b1[tid]; }
    if (tid < 4) qcur[tid] = 0;
    __syncthreads();

    const int ebase = g * EPG;
    #pragma unroll
    for (int i = 0; i < EPG/256; i++){
        int e = i*256 + tid;
        int s = src[ebase + e] - g*NPG;
        int d = dst[ebase + e] - g*NPG;
        srcL[e] = (u16)s; dstL[e] = (u16)d;
        atomicAdd(&degOut[s], 1);
        atomicAdd(&degIn[d], 1);
    }
    __syncthreads();

    if (tid < NPG){
        int din = degIn[tid], dout = degOut[tid];
        float ii = rsqrtf(fmaxf((float)din, 1.f));
        float io = rsqrtf(fmaxf((float)dout, 1.f));
        iiL[tid] = ii; ioL[tid] = io;
        sValL[tid] = (float)din * io;          // h0 = in_deg; s = h0*inv_out
        invInG[g*NPG + tid] = ii;
    }
    __syncthreads();

    // layer-1 scalar aggregation + bucket scatter (q = d/50 via mul-shift)
    #pragma unroll
    for (int i = 0; i < EPG/256; i++){
        int e = i*256 + tid;
        int s = srcL[e], d = dstL[e];
        atomicAdd(&sAgg[d], sValL[s]);
        int q = (d * 41) >> 11;                // exact d/50 for d in [0,200)
        int pos = atomicAdd(&qcur[q], 1);
        if (pos < QCAP)
            edgeBuf[((size_t)(g*4 + q))*QCAP + pos] = (u32)s | ((u32)(d - q*50) << 16);
    }
    __syncthreads();

    if (tid < 4) cntQ[g*4 + tid] = (qcur[tid] < QCAP) ? qcur[tid] : QCAP;
    if (tid < NPG) tL[tid] = sAgg[tid] * iiL[tid];
    __syncthreads();

    // h1sT[c][v] = bf16( relu(t[v]*w1[c]+b1[c]) * io[v] ), zero-pad v in [200,224)
    const size_t base = (size_t)g * HID * KP;
    #pragma unroll 4
    for (int i = 0; i < HID*KP/256; i++){
        int idx = i*256 + tid;
        int c = idx / KP, v = idx - c*KP;
        u16 o = 0;
        if (v < NPG)
            o = f2bf(fmaxf(fmaf(tL[v], w1L[c], b1L[c]), 0.f) * ioL[v]);
        h1sT[base + idx] = o;
    }
}

// ---------------------------------------------------------------------------
// K2 (fused, quarter-split): block = (graph g, dst-quarter q), 50 rows.
//   A[dl][s] edge counts built in 29.7KB LDS from pre-bucketed edges;
//   Z = A @ h1s^T; H = Z @ W2; h2 = relu(H*invIn + b2); hg += sum_v h2.
// A-frag: A[m=lr][k=quad*8+j]; B-frag: B[k=quad*8+j][n=lr]; C/D: col=lr,row=quad*4+r
// ---------------------------------------------------------------------------
__global__ __launch_bounds__(256, 4) void k_fused_graph(
    const u32* __restrict__ edgeBuf, const int* __restrict__ cntQ,
    const u16* __restrict__ h1sT, const u16* __restrict__ W2T,
    const float* __restrict__ invInG, const float* __restrict__ b2,
    float* __restrict__ hg)
{
    __shared__ __align__(16) u16 AZ[RQ*AP];   // 29.7 KB: dense A, then Z (64xZP)
    __shared__ float invInL[RQ];
    __shared__ float b2L[HID];
    __shared__ float poolL[HID];

    const int bid = blockIdx.x, tid = threadIdx.x;
    const int g = bid >> 2, q = bid & 3;
    u32* az32 = (u32*)AZ;
    uint4* az4 = (uint4*)AZ;

    #pragma unroll
    for (int i = 0; i < 8; i++){
        int idx = i*256 + tid;
        if (idx < RQ*AP/8) az4[idx] = make_uint4(0,0,0,0);
    }
    if (tid < HID){ b2L[tid] = b2[tid]; poolL[tid] = 0.f; }
    if (tid < RQ) invInL[tid] = (tid < 50) ? invInG[g*NPG + q*50 + tid] : 0.f;
    __syncthreads();

    // build A counts from this block's bucket (u32-packed u16 atomics)
    const int cnt = cntQ[bid];
    const u32* eb = edgeBuf + (size_t)bid * QCAP;
    for (int i = tid; i < cnt; i += 256){
        u32 e = eb[i];
        int s = e & 0xFFFF, dl = e >> 16;
        int idx = dl*AP + s;
        atomicAdd(&az32[idx >> 1], 1u << (16*(idx & 1)));
    }
    __syncthreads();

    // u16 counts -> bf16 in place (small ints: exact)
    for (int i = tid; i < RQ*AP/2; i += 256){
        u32 wv = az32[i];
        if (wv)
            az32[i] = (u32)f2bf((float)(wv & 0xFFFFu)) | ((u32)f2bf((float)(wv >> 16)) << 16);
    }
    __syncthreads();

    const int w = tid >> 6, lane = tid & 63;
    const int wm = w >> 1, wn = w & 1;
    const int lr = lane & 15, quad = lane >> 4;

    f32x4 acc[2][4];
    const f32x4 fz = {0.f, 0.f, 0.f, 0.f};
    #pragma unroll
    for (int mi = 0; mi < 2; mi++)
        #pragma unroll
        for (int nt = 0; nt < 4; nt++) acc[mi][nt] = fz;

    // ---- GEMM1: Z = A(64x224) @ B, B[k=v'][n=c] = h1sT[g][c][v'], cols wn*64..+63
    {
        const u16* Bg = h1sT + (size_t)g * HID * KP + (size_t)(wn*64) * KP;
        bf16x8 bcur[4], bnxt[4];
        #pragma unroll
        for (int nt = 0; nt < 4; nt++)
            bcur[nt] = *(const bf16x8*)&Bg[(nt*16 + lr)*KP + quad*8];
        for (int ks = 0; ks < 7; ks++){
            if (ks < 6){
                #pragma unroll
                for (int nt = 0; nt < 4; nt++)
                    bnxt[nt] = *(const bf16x8*)&Bg[(nt*16 + lr)*KP + (ks+1)*32 + quad*8];
            }
            bf16x8 af[2];
            #pragma unroll
            for (int mi = 0; mi < 2; mi++)
                af[mi] = *(const bf16x8*)&AZ[((wm*2 + mi)*16 + lr)*AP + ks*32 + quad*8];
            #pragma unroll
            for (int mi = 0; mi < 2; mi++)
                #pragma unroll
                for (int nt = 0; nt < 4; nt++)
                    acc[mi][nt] = __builtin_amdgcn_mfma_f32_16x16x32_bf16(
                        af[mi], bcur[nt], acc[mi][nt], 0, 0, 0);
            #pragma unroll
            for (int nt = 0; nt < 4; nt++) bcur[nt] = bnxt[nt];
        }
    }
    __syncthreads();   // all A reads done; AZ now holds Z

    // write Z bf16 into AZ (64 x ZP)
    #pragma unroll
    for (int mi = 0; mi < 2; mi++)
        #pragma unroll
        for (int nt = 0; nt < 4; nt++)
            #pragma unroll
            for (int r = 0; r < 4; r++){
                int v = (wm*2 + mi)*16 + quad*4 + r;
                int c = wn*64 + nt*16 + lr;
                AZ[v*ZP + c] = f2bf(acc[mi][nt][r]);
            }
    __syncthreads();

    // ---- GEMM2: H = Z(64x128) @ W2, B[k=cin][n=cout] = W2T[cout][cin]
    #pragma unroll
    for (int mi = 0; mi < 2; mi++)
        #pragma unroll
        for (int nt = 0; nt < 4; nt++) acc[mi][nt] = fz;
    {
        const u16* Wg = W2T + (size_t)(wn*64) * HID;
        bf16x8 bcur[4], bnxt[4];
        #pragma unroll
        for (int nt = 0; nt < 4; nt++)
            bcur[nt] = *(const bf16x8*)&Wg[(nt*16 + lr)*HID + quad*8];
        for (int ks = 0; ks < 4; ks++){
            if (ks < 3){
                #pragma unroll
                for (int nt = 0; nt < 4; nt++)
                    bnxt[nt] = *(const bf16x8*)&Wg[(nt*16 + lr)*HID + (ks+1)*32 + quad*8];
            }
            bf16x8 af[2];
            #pragma unroll
            for (int mi = 0; mi < 2; mi++)
                af[mi] = *(const bf16x8*)&AZ[((wm*2 + mi)*16 + lr)*ZP + ks*32 + quad*8];
            #pragma unroll
            for (int mi = 0; mi < 2; mi++)
                #pragma unroll
                for (int nt = 0; nt < 4; nt++)
                    acc[mi][nt] = __builtin_amdgcn_mfma_f32_16x16x32_bf16(
                        af[mi], bcur[nt], acc[mi][nt], 0, 0, 0);
            #pragma unroll
            for (int nt = 0; nt < 4; nt++) bcur[nt] = bnxt[nt];
        }
    }

    // epilogue: h2 = relu(acc*invIn + b2); pool; global accumulate
    #pragma unroll
    for (int mi = 0; mi < 2; mi++)
        #pragma unroll
        for (int nt = 0; nt < 4; nt++){
            int c = wn*64 + nt*16 + lr;
            float s = 0.f;
            #pragma unroll
            for (int r = 0; r < 4; r++){
                int v = (wm*2 + mi)*16 + quad*4 + r;
                if (v < 50)
                    s += fmaxf(fmaf(acc[mi][nt][r], invInL[v], b2L[c]), 0.f);
            }
            atomicAdd(&poolL[c], s);
        }
    __syncthreads();
    if (tid < HID) atomicAdd(&hg[(size_t)g*HID + tid], poolL[tid] * (1.f / NPG));
}

// ---------------------------------------------------------------------------
// MLP layer, MFMA with hi/lo bf16 activation split (fp32-accurate):
//   O = relu( (Ahi + Alo) @ W + bias ), output re-split into bf16 hi/lo planes.
// Block: 512 threads = 8 waves (2k x 2m x 2n), BM=32, BN=64, in-block K-split,
// fragments loaded directly from global (L2-resident), LDS only for k-reduce.
// ---------------------------------------------------------------------------
template<int K, bool AF32>
__global__ __launch_bounds__(512) void k_mlp3(
    const void* __restrict__ Ahi_, const u16* __restrict__ Alo,
    const u16* __restrict__ WT, const float* __restrict__ bias,
    u16* __restrict__ Ohi, u16* __restrict__ Olo, int Nc)
{
    __shared__ float red[32][68];

    const int tid = threadIdx.x;
    const int w = tid >> 6, lane = tid & 63;
    const int kz = w >> 2, wm = (w >> 1) & 1, wn = w & 1;
    const int lr = lane & 15, quad = lane >> 4;
    const int row0 = blockIdx.x * 32, col0 = blockIdx.y * 64;
    const int m = row0 + wm*16 + lr;
    constexpr int KH = K / 2;
    const int k0 = kz * KH;

    const float* Af = (const float*)Ahi_;
    const u16*   Ah = (const u16*)Ahi_;

    const f32x4 fz = {0.f, 0.f, 0.f, 0.f};
    f32x4 acc[2] = {fz, fz};

    #pragma unroll
    for (int ks = 0; ks < KH/32; ks++){
        const int kk = k0 + ks*32 + quad*8;
        bf16x8 ahi, alo;
        if constexpr (AF32){
            float xs[8];
            *(float4*)&xs[0] = *(const float4*)&Af[(size_t)m*K + kk];
            *(float4*)&xs[4] = *(const float4*)&Af[(size_t)m*K + kk + 4];
            #pragma unroll
            for (int j = 0; j < 8; j++){
                u16 hh = f2bf(xs[j]);
                ahi[j] = (short)hh;
                alo[j] = (short)f2bf(xs[j] - bf2f(hh));
            }
        } else {
            ahi = *(const bf16x8*)&Ah[(size_t)m*K + kk];
            alo = *(const bf16x8*)&Alo[(size_t)m*K + kk];
        }
        #pragma unroll
        for (int nt = 0; nt < 2; nt++){
            int n = col0 + wn*32 + nt*16 + lr;
            bf16x8 b = *(const bf16x8*)&WT[(size_t)n*K + kk];
            acc[nt] = __builtin_amdgcn_mfma_f32_16x16x32_bf16(ahi, b, acc[nt], 0, 0, 0);
            acc[nt] = __builtin_amdgcn_mfma_f32_16x16x32_bf16(alo, b, acc[nt], 0, 0, 0);
        }
    }

    // in-block K reduction: kz=1 parks partials in LDS, kz=0 finishes
    if (kz == 1){
        #pragma unroll
        for (int nt = 0; nt < 2; nt++)
            #pragma unroll
            for (int r = 0; r < 4; r++)
                red[wm*16 + quad*4 + r][wn*32 + nt*16 + lr] = acc[nt][r];
    }
    __syncthreads();
    if (kz == 0){
        #pragma unroll
        for (int nt = 0; nt < 2; nt++)
            #pragma unroll
            for (int r = 0; r < 4; r++){
                int rr = wm*16 + quad*4 + r;
                int cc = wn*32 + nt*16 + lr;
                float v = acc[nt][r] + red[rr][cc] + bias[col0 + cc];
                v = fmaxf(v, 0.f);
                u16 hh = f2bf(v);
                size_t go = (size_t)(row0 + rr) * Nc + col0 + cc;
                Ohi[go] = hh;
                Olo[go] = f2bf(v - bf2f(hh));
            }
    }
}

// ---------------------------------------------------------------------------
// head: logits = (X4hi+X4lo) @ We + be; softmax -> out (dtype per flag)
// ---------------------------------------------------------------------------
__global__ __launch_bounds__(64) void k_head(
    const u16* __restrict__ Xhi, const u16* __restrict__ Xlo,
    const float* __restrict__ We, const float* __restrict__ be,
    void* __restrict__ out, const int* __restrict__ flag)
{
    const int g = blockIdx.x, lane = threadIdx.x;
    float part[10];
    #pragma unroll
    for (int c = 0; c < 10; c++) part[c] = 0.f;
    for (int k = lane; k < 512; k += 64){
        float x = bf2f(Xhi[(size_t)g*512 + k]) + bf2f(Xlo[(size_t)g*512 + k]);
        #pragma unroll
        for (int c = 0; c < 10; c++) part[c] = fmaf(x, We[k*10 + c], part[c]);
    }
    #pragma unroll
    for (int c = 0; c < 10; c++){
        float v = part[c];
        for (int off = 32; off > 0; off >>= 1) v += __shfl_down(v, off);
        part[c] = v;
    }
    if (lane == 0){
        const int f = *flag;
        #pragma unroll
        for (int c = 0; c < 10; c++) part[c] += be[c];
        float m = part[0];
        #pragma unroll
        for (int c = 1; c < 10; c++) m = fmaxf(m, part[c]);
        float e[10], s = 0.f;
        #pragma unroll
        for (int c = 0; c < 10; c++){ e[c] = __expf(part[c] - m); s += e[c]; }
        float inv = 1.f / s;
        #pragma unroll
        for (int c = 0; c < 10; c++){
            float p = e[c] * inv;
            if (f) ((float*)out)[g*10 + c] = p;
            else   ((u16*)out)[g*10 + c]  = f2bf(p);
        }
    }
}

// ---------------------------------------------------------------------------
extern "C" void kernel_launch(void* const* d_in, const int* in_sizes, int n_in,
                              void* d_out, int out_size, void* d_ws, size_t ws_size,
                              hipStream_t stream)
{
    const int* src = (const int*)d_in[0];
    const int* dst = (const int*)d_in[1];

    char* ws = (char*)d_ws;
    size_t o = 0;
    int*   flag     = (int*)  (ws + o); o += 16;
    float* wcanon   = (float*)(ws + o); o += ((size_t)O_END * 4 + 15) & ~(size_t)15;
    u16*   W2T      = (u16*)  (ws + o); o += (size_t)HID * HID * 2;
    u16*   WTa      = (u16*)  (ws + o); o += ((size_t)T_END * 2 + 15) & ~(size_t)15;  // 4.3 MB
    float* invIn    = (float*)(ws + o); o += (size_t)NN * 4;
    u32*   edgeBuf  = (u32*)  (ws + o); o += (size_t)NG * 4 * QCAP * 4;   // 16.8 MB
    int*   cntQ     = (int*)  (ws + o); o += (size_t)NG * 4 * 4;
    u16*   h1sT     = (u16*)  (ws + o); o += (size_t)NG * HID * KP * 2;   // 29.4 MB
    float* hg       = (float*)(ws + o); o += (size_t)NG * HID * 4;
    u16*   X1hi     = (u16*)  (ws + o); o += (size_t)NG * 512 * 2;
    u16*   X1lo     = (u16*)  (ws + o); o += (size_t)NG * 512 * 2;
    u16*   X2hi     = (u16*)  (ws + o); o += (size_t)NG * 1024 * 2;
    u16*   X2lo     = (u16*)  (ws + o); o += (size_t)NG * 1024 * 2;
    u16*   X3hi     = (u16*)  (ws + o); o += (size_t)NG * 1024 * 2;
    u16*   X3lo     = (u16*)  (ws + o); o += (size_t)NG * 1024 * 2;
    u16*   X4hi     = (u16*)  (ws + o); o += (size_t)NG * 512 * 2;
    u16*   X4lo     = (u16*)  (ws + o); o += (size_t)NG * 512 * 2;
    (void)ws_size; (void)in_sizes; (void)n_in; (void)out_size;

    k_detect<<<dim3(1), dim3(128), 0, stream>>>((const u16*)d_in[2], flag);

    Cvt cv;
    const int offs[15] = {O_W1,O_b1,O_W2,O_b2,O_Wa,O_ba,O_Wb,O_bb,O_Wc,O_bc,O_Wd,O_bd,O_We,O_be,O_END};
    for (int i = 0; i < 14; i++){ cv.src[i] = d_in[2 + i]; cv.off[i] = offs[i]; }
    cv.off[14] = offs[14];
    k_convert<<<dim3((O_END + 255)/256), dim3(256), 0, stream>>>(cv, wcanon, flag, O_END);
    k_w2t<<<dim3(64), dim3(256), 0, stream>>>(d_in[4], wcanon + O_W2, W2T, hg, flag);

    // transpose MLP weights to n-major bf16
    TD4 td;
    td.t[0] = { d_in[6],  O_Wa, 7,  512,  T_Wa, T_Wb };   // Wa: K=128,  N=512
    td.t[1] = { d_in[8],  O_Wb, 9,  1024, T_Wb, T_Wc };   // Wb: K=512,  N=1024
    td.t[2] = { d_in[10], O_Wc, 10, 1024, T_Wc, T_Wd };   // Wc: K=1024, N=1024
    td.t[3] = { d_in[12], O_Wd, 10, 512,  T_Wd, T_END };  // Wd: K=1024, N=512
    k_wt<<<dim3((T_END + 255)/256), dim3(256), 0, stream>>>(td, wcanon, WTa, flag, T_END);

    const float *W1 = wcanon+O_W1, *b1 = wcanon+O_b1, *b2 = wcanon+O_b2;
    const float *ba = wcanon+O_ba, *bb = wcanon+O_bb, *bc = wcanon+O_bc, *bd = wcanon+O_bd;
    const float *We = wcanon+O_We, *be = wcanon+O_be;

    // K1: degrees + layer1 + edge bucketing
    k_graph_l1<<<dim3(NG), dim3(256), 0, stream>>>(
        src, dst, W1, b1, invIn, h1sT, edgeBuf, cntQ);

    // K2 fused: quarter-split dense-A MFMA x2 + pooling -> hg (2048 blocks)
    k_fused_graph<<<dim3(NG*4), dim3(256), 0, stream>>>(
        edgeBuf, cntQ, h1sT, W2T, invIn, b2, hg);

    // MLP: MFMA hi/lo-split layers (BM=32, BN=64, 512 threads)
    k_mlp3<128,  true ><<<dim3(16, 8),  dim3(512), 0, stream>>>(hg,   nullptr, WTa + T_Wa, ba, X1hi, X1lo, 512);
    k_mlp3<512,  false><<<dim3(16, 16), dim3(512), 0, stream>>>(X1hi, X1lo,    WTa + T_Wb, bb, X2hi, X2lo, 1024);
    k_mlp3<1024, false><<<dim3(16, 16), dim3(512), 0, stream>>>(X2hi, X2lo,    WTa + T_Wc, bc, X3hi, X3lo, 1024);
    k_mlp3<1024, false><<<dim3(16, 8),  dim3(512), 0, stream>>>(X3hi, X3lo,    WTa + T_Wd, bd, X4hi, X4lo, 512);

    // head + softmax
    k_head<<<dim3(NG), dim3(64), 0, stream>>>(X4hi, X4lo, We, be, d_out, flag);
}